// Round 10
// baseline (324.001 us; speedup 1.0000x reference)
//
#include <hip/hip_runtime.h>
#include <hip/hip_bf16.h>

typedef __attribute__((ext_vector_type(8))) short short8;
typedef __attribute__((ext_vector_type(4))) float floatx4;
typedef __attribute__((ext_vector_type(4))) unsigned short ushort4v;

#define DEVI __device__ __forceinline__

// ---------------- constants ----------------
// B=4, N=512, C_IN=256, RES=7, SR=2, FC_DIM=1024, OUT_CH=94
// M = B*N = 2048 rows, K1 = 256*7*7 = 12544

DEVI unsigned short f2bf(float v) {
  union { __hip_bfloat16 h; unsigned short u; } cv;
  cv.h = __float2bfloat16(v);
  return cv.u;
}

DEVI void gload16(const void* gptr, void* lptr) {
  __builtin_amdgcn_global_load_lds(
      (const __attribute__((address_space(1))) unsigned int*)gptr,
      (__attribute__((address_space(3))) unsigned int*)(unsigned long long)(uintptr_t)lptr,
      16, 0, 0);
}

// ---------------- weight conversion (vectorized: 4 floats -> 4 bf16 / thread) ----------------
__global__ void cvt_bf16x4_kernel(const float4* __restrict__ src,
                                  ushort4v* __restrict__ dst, size_t n4) {
  size_t i = (size_t)blockIdx.x * blockDim.x + threadIdx.x;
  if (i >= n4) return;
  float4 v = src[i];
  ushort4v o;
  o[0] = f2bf(v.x); o[1] = f2bf(v.y); o[2] = f2bf(v.z); o[3] = f2bf(v.w);
  dst[i] = o;
}

// pred_w (94x1024) -> padded (96x1024) bf16, rows 94..95 zero
__global__ void cvt_pad_pred_kernel(const float* __restrict__ src,
                                    unsigned short* __restrict__ dst) {
  int i = blockIdx.x * blockDim.x + threadIdx.x;
  if (i >= 96 * 1024) return;
  int row = i >> 10;
  dst[i] = (row < 94) ? f2bf(src[i]) : (unsigned short)0;
}

// ---------------- ROI align v7: gload16 staging + LDS cvt pass + W-in-LDS ----------------
// Out[ch][cell] = sum_{r,c} P[ch][r*16+c] * wy[py][r] * wx[px][c].
// P: staged f32 via global_load_lds (R7's proven coalesced path), then ONE LDS->LDS
// cvt pass to a bf16 tile. W: materialized once per block (49x264 bf16).
// Hot loop: 3x ds_read_b128 + 2x MFMA per k-step, zero VALU.
// grid (2048 boxes, 8 channel-octets of 32); 77 KB LDS -> 2 blocks/CU.
__global__ __launch_bounds__(256) void roi_mm4_kernel(
    const float* __restrict__ p3, const float* __restrict__ p4,
    const float* __restrict__ p5, const float* __restrict__ bbox,
    const int* __restrict__ aid, unsigned short* __restrict__ X) {
  constexpr int PS = 260;                  // f32 per-channel stride
  constexpr int SB = 264;                  // bf16 per-row stride (shorts)
  __shared__ float Pf[32 * PS];            // 33280 B
  __shared__ unsigned short Pb[32 * SB];   // 16896 B
  __shared__ unsigned short Wl[49 * SB];   // 25872 B
  __shared__ float wyx[238];               // wy [7][17] @0, wx [7][17] @119
  __shared__ int sy0[14], sx0[14];
  __shared__ float sly[14], slx[14];

  const int box = blockIdx.x;
  const int oct = blockIdx.y;              // channels oct*32 ..
  const int b = box >> 9;
  const int tid = threadIdx.x;
  const int lane = tid & 63, wid = tid >> 6;

  const int lvl = aid[box] / 3;
  const int H = 64 >> lvl;
  const int HH = H * H;
  const float* base = (lvl == 0) ? p3 : ((lvl == 1) ? p4 : p5);
  const float scale = 0.125f / (float)(1 << lvl);

  // ---- phase A: sample grid ----
  if (tid < 28) {
    int s = tid;
    bool isY = s < 14;
    int k = isY ? s : s - 14;
    float lo = bbox[box * 4 + (isY ? 0 : 1)];
    float hi = bbox[box * 4 + (isY ? 2 : 3)];
    float t = lo * scale - 0.5f;
    float cell = (hi - lo) * scale * (1.0f / 7.0f);
    float pos = t + ((float)k + 0.5f) * 0.5f * cell;   // S=14 samples, SR=2
    pos = fminf(fmaxf(pos, 0.0f), (float)(H - 1));
    int i0 = (int)floorf(pos);
    if (i0 > H - 2) i0 = H - 2;        // fr=1 reproduces the clamp
    float fr = pos - (float)i0;
    if (isY) { sy0[k] = i0; sly[k] = fr; }
    else     { sx0[k] = i0; slx[k] = fr; }
  }
  __syncthreads();

  const int ryb = min(sy0[0], H - 16);   // monotone grid -> sy0[0]/sx0[0] are minima
  const int rxb = min(sx0[0], H - 16);
  const float* fb = base + ((size_t)b * 256 + oct * 32) * HH + ryb * H + rxb;

  // ---- phase B1: separable pooled weights wy[7][16], wx[7][16] (stride 17) ----
  if (tid < 224) {
    int j = tid;
    bool isY = j < 112;
    int k2 = isY ? j : j - 112;
    int py = k2 >> 4, r = k2 & 15;
    int o0 = isY ? ryb : rxb;
    float acc = 0.f;
#pragma unroll
    for (int ss = 0; ss < 2; ++ss) {
      int s = 2 * py + ss;
      int rel = (isY ? sy0[s] : sx0[s]) - o0;
      float fr = isY ? sly[s] : slx[s];
      if (r == rel)     acc += 1.0f - fr;
      if (r == rel + 1) acc += fr;
    }
    wyx[(isY ? 0 : 119) + py * 17 + r] = acc * 0.5f;
  }

  // ---- phase B2: stage P f32 via global_load_lds (1 wave-op = 1 channel's 1KB patch) ----
  {
    const int r = lane >> 2, c4 = (lane & 3) * 4;
    const float* src0 = fb + r * H + c4;
#pragma unroll
    for (int it = 0; it < 8; ++it) {
      int ch = it * 4 + wid;
      gload16(src0 + (size_t)ch * HH, &Pf[ch * PS] + lane * 4);
    }
  }
  __syncthreads();

  // ---- phase C1: cvt Pf (f32) -> Pb (bf16). thread: ch = tid&31, row-pair j = tid>>5 ----
  {
    const int cch = tid & 31, cj = tid >> 5;
    const float* pf = &Pf[cch * PS + cj * 32];
    unsigned short* pb = &Pb[cch * SB + cj * 32];
    unsigned int d[16];
#pragma unroll
    for (int m = 0; m < 8; ++m) {
      float4 v = *(const float4*)(pf + m * 4);
      d[2 * m]     = (unsigned int)f2bf(v.x) | ((unsigned int)f2bf(v.y) << 16);
      d[2 * m + 1] = (unsigned int)f2bf(v.z) | ((unsigned int)f2bf(v.w) << 16);
    }
#pragma unroll
    for (int m = 0; m < 4; ++m)
      *(uint4*)(pb + m * 8) = make_uint4(d[4 * m], d[4 * m + 1], d[4 * m + 2], d[4 * m + 3]);
  }

  // ---- phase C2: W fill (49 cells x 128 dwords) ----
  for (int i = tid; i < 49 * 128; i += 256) {
    int cell = i >> 7;
    int d = i & 127;
    int r = d >> 3;
    int c = (d & 7) * 2;
    int py = (cell * 37) >> 8;           // cell/7 for 0..55
    int px = cell - py * 7;
    float wyv = wyx[py * 17 + r];
    const float* wxp = &wyx[119 + px * 17 + c];
    unsigned int pk = (unsigned int)f2bf(wyv * wxp[0]) |
                      ((unsigned int)f2bf(wyv * wxp[1]) << 16);
    *(unsigned int*)&Wl[cell * SB + d * 2] = pk;
  }
  __syncthreads();

  // ---- phase D: MFMA, zero VALU in loop ----
  const int fr = lane & 15, fg = lane >> 4;
  const int chf = wid >> 1;                // 0..1 (16-ch fragment)
  const int cellb = (wid & 1) * 32;        // cell half
  const int cell0 = cellb + fr;            // <= 47, always valid
  const int cell1 = cellb + 16 + fr;       // may be >= 49 (store-masked)
  const int crow1 = min(cell1, 48);        // clamped B-row: affects only masked lanes

  floatx4 acc0 = (floatx4){0.f, 0.f, 0.f, 0.f};
  floatx4 acc1 = (floatx4){0.f, 0.f, 0.f, 0.f};

#pragma unroll
  for (int kk = 0; kk < 8; ++kk) {
    short8 af = *(const short8*)&Pb[(chf * 16 + fr) * SB + kk * 32 + fg * 8];
    short8 b0 = *(const short8*)&Wl[cell0 * SB + kk * 32 + fg * 8];
    short8 b1 = *(const short8*)&Wl[crow1 * SB + kk * 32 + fg * 8];
    acc0 = __builtin_amdgcn_mfma_f32_16x16x32_bf16(af, b0, acc0, 0, 0, 0);
    acc1 = __builtin_amdgcn_mfma_f32_16x16x32_bf16(af, b1, acc1, 0, 0, 0);
  }

  unsigned short* xb = X + (size_t)box * 12544 + (size_t)(oct * 32 + chf * 16) * 49;
#pragma unroll
  for (int q = 0; q < 4; ++q)
    xb[(fg * 4 + q) * 49 + cell0] = f2bf(acc0[q]);
  if (cell1 < 49) {
#pragma unroll
    for (int q = 0; q < 4; ++q)
      xb[(fg * 4 + q) * 49 + cell1] = f2bf(acc1[q]);
  }
}

// ---------------- GEMM v2: 128x128 tile, BK=64, T2 XOR-swizzle, split-K ----------------
template <int KSPLIT>
__global__ __launch_bounds__(256) void gemm_bt_swz(
    const unsigned short* __restrict__ A, const unsigned short* __restrict__ Bw,
    float* __restrict__ C, int M, int N, int K) {
  constexpr int BM = 128, BN = 128, BK = 64;
  __shared__ unsigned short As[BM * BK];   // 16 KB
  __shared__ unsigned short Bs[BN * BK];   // 16 KB

  const int tid = threadIdx.x;
  const int lane = tid & 63, wid = tid >> 6;
  const int wr = wid >> 1, wc = wid & 1;    // 2x2 waves, 64x64 each
  const int tm = blockIdx.x * BM, tn = blockIdx.y * BN;
  const int fr = lane & 15, fg = lane >> 4;

  const int kLen = K / KSPLIT;
  const int kTiles = kLen / BK;
  const int kBeg = blockIdx.z * kLen;
  float* Cz = C + (size_t)blockIdx.z * M * N;

  floatx4 acc[4][4];
#pragma unroll
  for (int i = 0; i < 4; ++i)
#pragma unroll
    for (int j = 0; j < 4; ++j)
      acc[i][j] = (floatx4){0.f, 0.f, 0.f, 0.f};

  for (int t = 0; t < kTiles; ++t) {
    const int k0 = kBeg + t * BK;
#pragma unroll
    for (int s = tid; s < BM * 8; s += 256) {
      int row = s >> 3, sl = s & 7;
      int slg = sl ^ (row & 7);
      gload16(&A[(size_t)(tm + row) * K + k0 + slg * 8], &As[s * 8]);
    }
#pragma unroll
    for (int s = tid; s < BN * 8; s += 256) {
      int row = s >> 3, sl = s & 7;
      int slg = sl ^ (row & 7);
      gload16(&Bw[(size_t)(tn + row) * K + k0 + slg * 8], &Bs[s * 8]);
    }
    __syncthreads();

#pragma unroll
    for (int kk = 0; kk < 2; ++kk) {
      short8 af[4], bf[4];
#pragma unroll
      for (int i = 0; i < 4; ++i) {
        int row = wr * 64 + i * 16 + fr;
        int sl = (kk * 4 + fg) ^ (row & 7);
        af[i] = *reinterpret_cast<const short8*>(&As[(row * 8 + sl) * 8]);
      }
#pragma unroll
      for (int j = 0; j < 4; ++j) {
        int row = wc * 64 + j * 16 + fr;
        int sl = (kk * 4 + fg) ^ (row & 7);
        bf[j] = *reinterpret_cast<const short8*>(&Bs[(row * 8 + sl) * 8]);
      }
#pragma unroll
      for (int i = 0; i < 4; ++i)
#pragma unroll
        for (int j = 0; j < 4; ++j)
          acc[i][j] = __builtin_amdgcn_mfma_f32_16x16x32_bf16(af[i], bf[j], acc[i][j], 0, 0, 0);
    }
    __syncthreads();
  }

#pragma unroll
  for (int i = 0; i < 4; ++i)
#pragma unroll
    for (int j = 0; j < 4; ++j)
#pragma unroll
      for (int q = 0; q < 4; ++q) {
        int rr = tm + wr * 64 + i * 16 + fg * 4 + q;
        int cc = tn + wc * 64 + j * 16 + fr;
        Cz[(size_t)rr * N + cc] = acc[i][j][q];
      }
}

// ---------------- old GEMM (pred head only) ----------------
template <int BM, int BN, int WAVES_M, int WAVES_N, int KSPLIT>
__global__ __launch_bounds__(256) void gemm_bt_kernel(
    const unsigned short* __restrict__ A, const unsigned short* __restrict__ Bw,
    float* __restrict__ C, int M, int N, int K) {
  constexpr int BK = 32;
  constexpr int WM = BM / WAVES_M, WN = BN / WAVES_N;
  constexpr int AF = WM / 16, BF = WN / 16;
  constexpr int ASLOT = BM * 4;
  constexpr int BSLOT = BN * 4;
  __shared__ unsigned short As[BM * BK];
  __shared__ unsigned short Bs[BN * BK];

  const int tid = threadIdx.x;
  const int lane = tid & 63, wid = tid >> 6;
  const int wr = wid / WAVES_N, wc = wid % WAVES_N;
  const int tm = blockIdx.x * BM, tn = blockIdx.y * BN;
  const int fr = lane & 15, fg = lane >> 4;

  const int kLen = K / KSPLIT;
  const int kBeg = blockIdx.z * kLen;
  float* Cz = C + (size_t)blockIdx.z * M * N;

  floatx4 acc[AF][BF];
#pragma unroll
  for (int i = 0; i < AF; ++i)
#pragma unroll
    for (int j = 0; j < BF; ++j)
      acc[i][j] = (floatx4){0.f, 0.f, 0.f, 0.f};

  for (int k0 = kBeg; k0 < kBeg + kLen; k0 += BK) {
#pragma unroll
    for (int s = tid; s < ASLOT; s += 256) {
      int row = s >> 2, kb = (s & 3) << 3;
      gload16(&A[(size_t)(tm + row) * K + k0 + kb], &As[s * 8]);
    }
#pragma unroll
    for (int s = tid; s < BSLOT; s += 256) {
      int row = s >> 2, kb = (s & 3) << 3;
      gload16(&Bw[(size_t)(tn + row) * K + k0 + kb], &Bs[s * 8]);
    }
    __syncthreads();

    short8 af[AF], bfv[BF];
#pragma unroll
    for (int i = 0; i < AF; ++i)
      af[i] = *reinterpret_cast<const short8*>(&As[(wr * WM + i * 16 + fr) * BK + fg * 8]);
#pragma unroll
    for (int j = 0; j < BF; ++j)
      bfv[j] = *reinterpret_cast<const short8*>(&Bs[(wc * WN + j * 16 + fr) * BK + fg * 8]);
#pragma unroll
    for (int i = 0; i < AF; ++i)
#pragma unroll
      for (int j = 0; j < BF; ++j)
        acc[i][j] = __builtin_amdgcn_mfma_f32_16x16x32_bf16(af[i], bfv[j], acc[i][j], 0, 0, 0);
    __syncthreads();
  }

#pragma unroll
  for (int i = 0; i < AF; ++i)
#pragma unroll
    for (int j = 0; j < BF; ++j)
#pragma unroll
      for (int q = 0; q < 4; ++q) {
        int rr = tm + wr * WM + i * 16 + fg * 4 + q;
        int cc = tn + wc * WN + j * 16 + fr;
        Cz[(size_t)rr * N + cc] = acc[i][j][q];
      }
}

// ---------------- BatchNorm (train mode) ----------------
// pass 1: reduce split-K partials + per-rowgroup stats. grid (Ncols/256, 128).
__global__ void bn_stats_red_kernel(const float* __restrict__ Yp, float* __restrict__ Yred,
                                    float* __restrict__ psum, float* __restrict__ psq,
                                    int Ncols, int rowsPer, int P, size_t pstride) {
  int c = blockIdx.x * blockDim.x + threadIdx.x;
  int r0 = blockIdx.y * rowsPer;
  float s = 0.f, ss = 0.f;
  for (int r = 0; r < rowsPer; ++r) {
    size_t idx = (size_t)(r0 + r) * Ncols + c;
    float v = Yp[idx];
    for (int p = 1; p < P; ++p) v += Yp[idx + (size_t)p * pstride];
    Yred[idx] = v;
    s += v;
    ss += v * v;
  }
  psum[(size_t)blockIdx.y * Ncols + c] = s;
  psq[(size_t)blockIdx.y * Ncols + c] = ss;
}

__global__ void bn_finalize_kernel(const float* __restrict__ psum, const float* __restrict__ psq,
                                   const float* __restrict__ g, const float* __restrict__ b,
                                   float* __restrict__ scale, float* __restrict__ shift,
                                   int Ncols, int P, float invM) {
  int c = blockIdx.x * blockDim.x + threadIdx.x;
  if (c >= Ncols) return;
  float s = 0.f, ss = 0.f;
  for (int p = 0; p < P; ++p) {
    s += psum[(size_t)p * Ncols + c];
    ss += psq[(size_t)p * Ncols + c];
  }
  float mean = s * invM;
  float var = ss * invM - mean * mean;
  float rstd = rsqrtf(var + 1e-5f);
  float sc = rstd * g[c];
  scale[c] = sc;
  shift[c] = b[c] - mean * sc;
}

// pass 2: apply, vectorized float4 -> 4x bf16 (FC divisible by 4)
__global__ void bn_apply4_kernel(const float4* __restrict__ Y, const float* __restrict__ scale,
                                 const float* __restrict__ shift, ushort4v* __restrict__ X,
                                 int colGroupsMask, int total4) {
  int i = blockIdx.x * blockDim.x + threadIdx.x;
  if (i >= total4) return;
  int c0 = (i & colGroupsMask) * 4;
  float4 v = Y[i];
  ushort4v o;
  o[0] = f2bf(fmaxf(v.x * scale[c0 + 0] + shift[c0 + 0], 0.0f));
  o[1] = f2bf(fmaxf(v.y * scale[c0 + 1] + shift[c0 + 1], 0.0f));
  o[2] = f2bf(fmaxf(v.z * scale[c0 + 2] + shift[c0 + 2], 0.0f));
  o[3] = f2bf(fmaxf(v.w * scale[c0 + 3] + shift[c0 + 3], 0.0f));
  X[i] = o;
}

// ---------------- decode ----------------
// Y3 holds KSPLIT=4 partials of (2048 x 96)
__global__ void decode_kernel(const float* __restrict__ Y3, const float* __restrict__ pb,
                              const float* __restrict__ anchors, const int* __restrict__ aid,
                              float* __restrict__ out) {
  int i = blockIdx.x * blockDim.x + threadIdx.x;
  if (i >= 2048 * 94) return;
  int bn = i / 94;
  int ch = i - bn * 94;
  size_t idx = (size_t)bn * 96 + ch;
  float v = Y3[idx] + Y3[idx + 2048 * 96] + Y3[idx + 2 * 2048 * 96] + Y3[idx + 3 * 2048 * 96];
  v += pb[ch];
  float o = v;
  if (ch >= 4 && ch < 22) {
    int q = ch - 4;
    int d = q % 6;   // within-class: 0,1=yx 2,3=lw 4,5=zh
    if (d < 2) {
      float stride_px = (float)(8 << (aid[bn] / 3));
      o = anchors[(size_t)bn * 4 + d] + v * stride_px;
    } else if (d < 4) {
      float cl = fminf(fmaxf(v, -4.0f), 4.0f);
      o = anchors[(size_t)bn * 4 + d] * expf(cl);
    }
  }
  out[i] = o;
}

// ---------------- launch ----------------
extern "C" void kernel_launch(void* const* d_in, const int* in_sizes, int n_in,
                              void* d_out, int out_size, void* d_ws, size_t ws_size,
                              hipStream_t stream) {
  const float* feat_p3   = (const float*)d_in[0];
  const float* feat_p4   = (const float*)d_in[1];
  const float* feat_p5   = (const float*)d_in[2];
  const float* bbox2d    = (const float*)d_in[3];
  const float* anchors   = (const float*)d_in[4];
  const int*   anchor_id = (const int*)d_in[5];
  const float* fc1_w     = (const float*)d_in[6];
  // d_in[7] fc1_b: cancels through train-mode BN (mean subtraction) — unused
  const float* bn1_g     = (const float*)d_in[8];
  const float* bn1_b     = (const float*)d_in[9];
  const float* fc2_w     = (const float*)d_in[10];
  // d_in[11] fc2_b: cancels — unused
  const float* bn2_g     = (const float*)d_in[12];
  const float* bn2_b     = (const float*)d_in[13];
  const float* pred_w    = (const float*)d_in[14];
  const float* pred_b    = (const float*)d_in[15];
  float* out = (float*)d_out;

  const int M = 2048;          // B*N
  const int K1 = 12544;        // 256*7*7
  const int FC = 1024;
  const int RG = 128;          // BN stats row-groups

  char* ws = (char*)d_ws;
  auto alloc = [&](size_t bytes) -> char* {
    char* p = ws;
    ws += (bytes + 255) & ~(size_t)255;
    return p;
  };
  unsigned short* W1b  = (unsigned short*)alloc((size_t)FC * K1 * 2);
  unsigned short* W2b  = (unsigned short*)alloc((size_t)FC * FC * 2);
  unsigned short* W3b  = (unsigned short*)alloc((size_t)96 * FC * 2);
  unsigned short* X1   = (unsigned short*)alloc((size_t)M * K1 * 2);
  float*          Yp   = (float*)alloc((size_t)4 * M * FC * 4);  // split-K partials
  float*          Yr   = (float*)alloc((size_t)M * FC * 4);      // reduced Y
  unsigned short* X2   = (unsigned short*)alloc((size_t)M * FC * 2);
  unsigned short* X3   = (unsigned short*)alloc((size_t)M * FC * 2);
  float*          Y3   = (float*)alloc((size_t)4 * M * 96 * 4);
  float*          ps   = (float*)alloc((size_t)RG * FC * 4);
  float*          pq   = (float*)alloc((size_t)RG * FC * 4);
  float*          sc1  = (float*)alloc((size_t)FC * 4);
  float*          sh1  = (float*)alloc((size_t)FC * 4);
  float*          sc2  = (float*)alloc((size_t)FC * 4);
  float*          sh2  = (float*)alloc((size_t)FC * 4);

  // weight conversions (must redo each call — no cross-call state allowed)
  {
    size_t n4 = (size_t)FC * K1 / 4;
    cvt_bf16x4_kernel<<<(unsigned)((n4 + 255) / 256), 256, 0, stream>>>(
        (const float4*)fc1_w, (ushort4v*)W1b, n4);
  }
  {
    size_t n4 = (size_t)FC * FC / 4;
    cvt_bf16x4_kernel<<<(unsigned)((n4 + 255) / 256), 256, 0, stream>>>(
        (const float4*)fc2_w, (ushort4v*)W2b, n4);
  }
  cvt_pad_pred_kernel<<<(96 * 1024) / 256, 256, 0, stream>>>(pred_w, W3b);

  // ROI align (fused, gload16 staging + LDS cvt + W-in-LDS) -> X1 (2048 x 12544) bf16
  roi_mm4_kernel<<<dim3(2048, 8), 256, 0, stream>>>(feat_p3, feat_p4, feat_p5,
                                                    bbox2d, anchor_id, X1);

  // fc1: X1 (2048x12544) @ W1^T -> Yp (4 partials of 2048x1024)
  gemm_bt_swz<4><<<dim3(M / 128, FC / 128, 4), 256, 0, stream>>>(X1, W1b, Yp, M, FC, K1);

  // BN1: reduce partials + stats (512 blocks), finalize, apply+ReLU -> X2 bf16
  bn_stats_red_kernel<<<dim3(FC / 256, RG), 256, 0, stream>>>(Yp, Yr, ps, pq, FC, M / RG, 4, (size_t)M * FC);
  bn_finalize_kernel<<<FC / 256, 256, 0, stream>>>(ps, pq, bn1_g, bn1_b, sc1, sh1, FC, RG, 1.0f / M);
  bn_apply4_kernel<<<(M * FC / 4) / 256, 256, 0, stream>>>(
      (const float4*)Yr, sc1, sh1, (ushort4v*)X2, FC / 4 - 1, M * FC / 4);

  // fc2: X2 @ W2^T -> Yp (2 partials)
  gemm_bt_swz<2><<<dim3(M / 128, FC / 128, 2), 256, 0, stream>>>(X2, W2b, Yp, M, FC, FC);

  // BN2 + ReLU -> X3 bf16
  bn_stats_red_kernel<<<dim3(FC / 256, RG), 256, 0, stream>>>(Yp, Yr, ps, pq, FC, M / RG, 2, (size_t)M * FC);
  bn_finalize_kernel<<<FC / 256, 256, 0, stream>>>(ps, pq, bn2_g, bn2_b, sc2, sh2, FC, RG, 1.0f / M);
  bn_apply4_kernel<<<(M * FC / 4) / 256, 256, 0, stream>>>(
      (const float4*)Yr, sc2, sh2, (ushort4v*)X3, FC / 4 - 1, M * FC / 4);

  // pred head: X3 @ W3p^T -> Y3 (split-K=4 partials of 2048 x 96)
  gemm_bt_kernel<64, 96, 2, 2, 4><<<dim3(M / 64, 1, 4), 256, 0, stream>>>(X3, W3b, Y3, M, 96, FC);

  // decode -> out (2048 x 94)
  decode_kernel<<<(2048 * 94 + 255) / 256, 256, 0, stream>>>(Y3, pred_b, anchors, anchor_id, out);
}

// Round 11
// 259.325 us; speedup vs baseline: 1.2494x; 1.2494x over previous
//
#include <hip/hip_runtime.h>
#include <hip/hip_bf16.h>

typedef __attribute__((ext_vector_type(8))) short short8;
typedef __attribute__((ext_vector_type(4))) float floatx4;
typedef __attribute__((ext_vector_type(4))) unsigned short ushort4v;

#define DEVI __device__ __forceinline__

// ---------------- constants ----------------
// B=4, N=512, C_IN=256, RES=7, SR=2, FC_DIM=1024, OUT_CH=94
// M = B*N = 2048 rows, K1 = 256*7*7 = 12544

DEVI unsigned short f2bf(float v) {
  union { __hip_bfloat16 h; unsigned short u; } cv;
  cv.h = __float2bfloat16(v);
  return cv.u;
}
DEVI short f2bfs(float v) { return (short)f2bf(v); }

DEVI void gload16(const void* gptr, void* lptr) {
  __builtin_amdgcn_global_load_lds(
      (const __attribute__((address_space(1))) unsigned int*)gptr,
      (__attribute__((address_space(3))) unsigned int*)(unsigned long long)(uintptr_t)lptr,
      16, 0, 0);
}

// ---------------- weight conversion (vectorized: 4 floats -> 4 bf16 / thread) ----------------
__global__ void cvt_bf16x4_kernel(const float4* __restrict__ src,
                                  ushort4v* __restrict__ dst, size_t n4) {
  size_t i = (size_t)blockIdx.x * blockDim.x + threadIdx.x;
  if (i >= n4) return;
  float4 v = src[i];
  ushort4v o;
  o[0] = f2bf(v.x); o[1] = f2bf(v.y); o[2] = f2bf(v.z); o[3] = f2bf(v.w);
  dst[i] = o;
}

// pred_w (94x1024) -> padded (96x1024) bf16, rows 94..95 zero
__global__ void cvt_pad_pred_kernel(const float* __restrict__ src,
                                    unsigned short* __restrict__ dst) {
  int i = blockIdx.x * blockDim.x + threadIdx.x;
  if (i >= 96 * 1024) return;
  int row = i >> 10;
  dst[i] = (row < 94) ? f2bf(src[i]) : (unsigned short)0;
}

// ---------------- ROI align v8 (roi_mm5): R7 backbone + hoisted B-invariants ----------------
// Out[ch][cell] = sum_{r,c} P[ch][r*16+c] * wy[py][r] * wx[px][c].
// P staged f32 via global_load_lds (proven R7 path, 34.5 KB LDS, 4 blocks/CU).
// Per thread: ONE cell (wave = cell-quarter), B x-slice (8) and wy sequence (8)
// hoisted to registers; loop = 4x ds_read_b128 + 8 pk-cvt(A) + 8 mul + 4 pk(B) + 2 MFMA.
// grid (2048 boxes, 8 channel-octets of 32).
__global__ __launch_bounds__(256) void roi_mm5_kernel(
    const float* __restrict__ p3, const float* __restrict__ p4,
    const float* __restrict__ p5, const float* __restrict__ bbox,
    const int* __restrict__ aid, unsigned short* __restrict__ X) {
  constexpr int PS = 260;   // f32 per-channel stride
  __shared__ float Pf[32 * PS];            // 33280 B
  __shared__ float wyx[238];               // wy [7][17] @0, wx [7][17] @119
  __shared__ int sy0[14], sx0[14];
  __shared__ float sly[14], slx[14];

  const int box = blockIdx.x;
  const int oct = blockIdx.y;              // channels oct*32 ..
  const int b = box >> 9;
  const int tid = threadIdx.x;
  const int lane = tid & 63, wid = tid >> 6;

  const int lvl = aid[box] / 3;
  const int H = 64 >> lvl;
  const int HH = H * H;
  const float* base = (lvl == 0) ? p3 : ((lvl == 1) ? p4 : p5);
  const float scale = 0.125f / (float)(1 << lvl);

  // ---- phase A: sample grid ----
  if (tid < 28) {
    int s = tid;
    bool isY = s < 14;
    int k = isY ? s : s - 14;
    float lo = bbox[box * 4 + (isY ? 0 : 1)];
    float hi = bbox[box * 4 + (isY ? 2 : 3)];
    float t = lo * scale - 0.5f;
    float cell = (hi - lo) * scale * (1.0f / 7.0f);
    float pos = t + ((float)k + 0.5f) * 0.5f * cell;   // S=14 samples, SR=2
    pos = fminf(fmaxf(pos, 0.0f), (float)(H - 1));
    int i0 = (int)floorf(pos);
    if (i0 > H - 2) i0 = H - 2;        // fr=1 reproduces the clamp
    float fr = pos - (float)i0;
    if (isY) { sy0[k] = i0; sly[k] = fr; }
    else     { sx0[k] = i0; slx[k] = fr; }
  }
  __syncthreads();

  const int ryb = min(sy0[0], H - 16);   // monotone grid -> sy0[0]/sx0[0] are minima
  const int rxb = min(sx0[0], H - 16);
  const float* fb = base + ((size_t)b * 256 + oct * 32) * HH + ryb * H + rxb;

  // ---- phase B1: separable pooled weights wy[7][16], wx[7][16] (stride 17) ----
  if (tid < 224) {
    int j = tid;
    bool isY = j < 112;
    int k2 = isY ? j : j - 112;
    int py = k2 >> 4, r = k2 & 15;
    int o0 = isY ? ryb : rxb;
    float acc = 0.f;
#pragma unroll
    for (int ss = 0; ss < 2; ++ss) {
      int s = 2 * py + ss;
      int rel = (isY ? sy0[s] : sx0[s]) - o0;
      float fr = isY ? sly[s] : slx[s];
      if (r == rel)     acc += 1.0f - fr;
      if (r == rel + 1) acc += fr;
    }
    wyx[(isY ? 0 : 119) + py * 17 + r] = acc * 0.5f;
  }

  // ---- phase B2: stage P f32 via global_load_lds (1 wave-op = 1 channel's 1KB patch) ----
  {
    const int r = lane >> 2, c4 = (lane & 3) * 4;
    const float* src0 = fb + r * H + c4;
#pragma unroll
    for (int it = 0; it < 8; ++it) {
      int ch = it * 4 + wid;
      gload16(src0 + (size_t)ch * HH, &Pf[ch * PS] + lane * 4);
    }
  }
  __syncthreads();

  // ---- phase C: MFMA. wave = cell-quarter; thread covers both 16-ch fragments ----
  const int fr = lane & 15, fg = lane >> 4;
  const int cell = wid * 16 + fr;          // 0..63; valid < 49
  const int py = (cell * 37) >> 8;         // cell/7 for 0..63 (py<=9: garbage reads, masked)
  const int px = cell - py * 7;

  // hoist B invariants: x-slice (kk-invariant) and wy stride-2 sequence
  float xv[8], wyv[8];
  {
    const float* xp = &wyx[119 + px * 17 + (fg & 1) * 8];
#pragma unroll
    for (int e = 0; e < 8; ++e) xv[e] = xp[e];
    const float* wp = &wyx[py * 17 + (fg >> 1)];
#pragma unroll
    for (int kk = 0; kk < 8; ++kk) wyv[kk] = wp[2 * kk];
  }

  floatx4 acc0 = (floatx4){0.f, 0.f, 0.f, 0.f};   // chf = 0
  floatx4 acc1 = (floatx4){0.f, 0.f, 0.f, 0.f};   // chf = 1

#pragma unroll
  for (int kk = 0; kk < 8; ++kk) {
    const float* a0p = &Pf[fr * PS + kk * 32 + fg * 8];
    const float* a1p = &Pf[(16 + fr) * PS + kk * 32 + fg * 8];
    floatx4 a00 = *(const floatx4*)a0p, a01 = *(const floatx4*)(a0p + 4);
    floatx4 a10 = *(const floatx4*)a1p, a11 = *(const floatx4*)(a1p + 4);
    short8 af0, af1, bfr;
    af0[0] = f2bfs(a00[0]); af0[1] = f2bfs(a00[1]); af0[2] = f2bfs(a00[2]); af0[3] = f2bfs(a00[3]);
    af0[4] = f2bfs(a01[0]); af0[5] = f2bfs(a01[1]); af0[6] = f2bfs(a01[2]); af0[7] = f2bfs(a01[3]);
    af1[0] = f2bfs(a10[0]); af1[1] = f2bfs(a10[1]); af1[2] = f2bfs(a10[2]); af1[3] = f2bfs(a10[3]);
    af1[4] = f2bfs(a11[0]); af1[5] = f2bfs(a11[1]); af1[6] = f2bfs(a11[2]); af1[7] = f2bfs(a11[3]);
    const float w = wyv[kk];
#pragma unroll
    for (int e = 0; e < 8; ++e) bfr[e] = f2bfs(w * xv[e]);
    acc0 = __builtin_amdgcn_mfma_f32_16x16x32_bf16(af0, bfr, acc0, 0, 0, 0);
    acc1 = __builtin_amdgcn_mfma_f32_16x16x32_bf16(af1, bfr, acc1, 0, 0, 0);
  }

  if (cell < 49) {
    unsigned short* xb = X + (size_t)box * 12544 + (size_t)(oct * 32) * 49 + cell;
#pragma unroll
    for (int q = 0; q < 4; ++q) {
      xb[(fg * 4 + q) * 49] = f2bf(acc0[q]);
      xb[(16 + fg * 4 + q) * 49] = f2bf(acc1[q]);
    }
  }
}

// ---------------- GEMM v2: 128x128 tile, BK=64, T2 XOR-swizzle, split-K ----------------
template <int KSPLIT>
__global__ __launch_bounds__(256) void gemm_bt_swz(
    const unsigned short* __restrict__ A, const unsigned short* __restrict__ Bw,
    float* __restrict__ C, int M, int N, int K) {
  constexpr int BM = 128, BN = 128, BK = 64;
  __shared__ unsigned short As[BM * BK];   // 16 KB
  __shared__ unsigned short Bs[BN * BK];   // 16 KB

  const int tid = threadIdx.x;
  const int lane = tid & 63, wid = tid >> 6;
  const int wr = wid >> 1, wc = wid & 1;    // 2x2 waves, 64x64 each
  const int tm = blockIdx.x * BM, tn = blockIdx.y * BN;
  const int fr = lane & 15, fg = lane >> 4;

  const int kLen = K / KSPLIT;
  const int kTiles = kLen / BK;
  const int kBeg = blockIdx.z * kLen;
  float* Cz = C + (size_t)blockIdx.z * M * N;

  floatx4 acc[4][4];
#pragma unroll
  for (int i = 0; i < 4; ++i)
#pragma unroll
    for (int j = 0; j < 4; ++j)
      acc[i][j] = (floatx4){0.f, 0.f, 0.f, 0.f};

  for (int t = 0; t < kTiles; ++t) {
    const int k0 = kBeg + t * BK;
#pragma unroll
    for (int s = tid; s < BM * 8; s += 256) {
      int row = s >> 3, sl = s & 7;
      int slg = sl ^ (row & 7);
      gload16(&A[(size_t)(tm + row) * K + k0 + slg * 8], &As[s * 8]);
    }
#pragma unroll
    for (int s = tid; s < BN * 8; s += 256) {
      int row = s >> 3, sl = s & 7;
      int slg = sl ^ (row & 7);
      gload16(&Bw[(size_t)(tn + row) * K + k0 + slg * 8], &Bs[s * 8]);
    }
    __syncthreads();

#pragma unroll
    for (int kk = 0; kk < 2; ++kk) {
      short8 af[4], bf[4];
#pragma unroll
      for (int i = 0; i < 4; ++i) {
        int row = wr * 64 + i * 16 + fr;
        int sl = (kk * 4 + fg) ^ (row & 7);
        af[i] = *reinterpret_cast<const short8*>(&As[(row * 8 + sl) * 8]);
      }
#pragma unroll
      for (int j = 0; j < 4; ++j) {
        int row = wc * 64 + j * 16 + fr;
        int sl = (kk * 4 + fg) ^ (row & 7);
        bf[j] = *reinterpret_cast<const short8*>(&Bs[(row * 8 + sl) * 8]);
      }
#pragma unroll
      for (int i = 0; i < 4; ++i)
#pragma unroll
        for (int j = 0; j < 4; ++j)
          acc[i][j] = __builtin_amdgcn_mfma_f32_16x16x32_bf16(af[i], bf[j], acc[i][j], 0, 0, 0);
    }
    __syncthreads();
  }

#pragma unroll
  for (int i = 0; i < 4; ++i)
#pragma unroll
    for (int j = 0; j < 4; ++j)
#pragma unroll
      for (int q = 0; q < 4; ++q) {
        int rr = tm + wr * 64 + i * 16 + fg * 4 + q;
        int cc = tn + wc * 64 + j * 16 + fr;
        Cz[(size_t)rr * N + cc] = acc[i][j][q];
      }
}

// ---------------- old GEMM (pred head only) ----------------
template <int BM, int BN, int WAVES_M, int WAVES_N, int KSPLIT>
__global__ __launch_bounds__(256) void gemm_bt_kernel(
    const unsigned short* __restrict__ A, const unsigned short* __restrict__ Bw,
    float* __restrict__ C, int M, int N, int K) {
  constexpr int BK = 32;
  constexpr int WM = BM / WAVES_M, WN = BN / WAVES_N;
  constexpr int AF = WM / 16, BF = WN / 16;
  constexpr int ASLOT = BM * 4;
  constexpr int BSLOT = BN * 4;
  __shared__ unsigned short As[BM * BK];
  __shared__ unsigned short Bs[BN * BK];

  const int tid = threadIdx.x;
  const int lane = tid & 63, wid = tid >> 6;
  const int wr = wid / WAVES_N, wc = wid % WAVES_N;
  const int tm = blockIdx.x * BM, tn = blockIdx.y * BN;
  const int fr = lane & 15, fg = lane >> 4;

  const int kLen = K / KSPLIT;
  const int kBeg = blockIdx.z * kLen;
  float* Cz = C + (size_t)blockIdx.z * M * N;

  floatx4 acc[AF][BF];
#pragma unroll
  for (int i = 0; i < AF; ++i)
#pragma unroll
    for (int j = 0; j < BF; ++j)
      acc[i][j] = (floatx4){0.f, 0.f, 0.f, 0.f};

  for (int k0 = kBeg; k0 < kBeg + kLen; k0 += BK) {
#pragma unroll
    for (int s = tid; s < ASLOT; s += 256) {
      int row = s >> 2, kb = (s & 3) << 3;
      gload16(&A[(size_t)(tm + row) * K + k0 + kb], &As[s * 8]);
    }
#pragma unroll
    for (int s = tid; s < BSLOT; s += 256) {
      int row = s >> 2, kb = (s & 3) << 3;
      gload16(&Bw[(size_t)(tn + row) * K + k0 + kb], &Bs[s * 8]);
    }
    __syncthreads();

    short8 af[AF], bfv[BF];
#pragma unroll
    for (int i = 0; i < AF; ++i)
      af[i] = *reinterpret_cast<const short8*>(&As[(wr * WM + i * 16 + fr) * BK + fg * 8]);
#pragma unroll
    for (int j = 0; j < BF; ++j)
      bfv[j] = *reinterpret_cast<const short8*>(&Bs[(wc * WN + j * 16 + fr) * BK + fg * 8]);
#pragma unroll
    for (int i = 0; i < AF; ++i)
#pragma unroll
      for (int j = 0; j < BF; ++j)
        acc[i][j] = __builtin_amdgcn_mfma_f32_16x16x32_bf16(af[i], bfv[j], acc[i][j], 0, 0, 0);
    __syncthreads();
  }

#pragma unroll
  for (int i = 0; i < AF; ++i)
#pragma unroll
    for (int j = 0; j < BF; ++j)
#pragma unroll
      for (int q = 0; q < 4; ++q) {
        int rr = tm + wr * WM + i * 16 + fg * 4 + q;
        int cc = tn + wc * WN + j * 16 + fr;
        Cz[(size_t)rr * N + cc] = acc[i][j][q];
      }
}

// ---------------- BatchNorm (train mode) ----------------
// pass 1: reduce split-K partials + per-rowgroup stats. grid (Ncols/256, 128).
__global__ void bn_stats_red_kernel(const float* __restrict__ Yp, float* __restrict__ Yred,
                                    float* __restrict__ psum, float* __restrict__ psq,
                                    int Ncols, int rowsPer, int P, size_t pstride) {
  int c = blockIdx.x * blockDim.x + threadIdx.x;
  int r0 = blockIdx.y * rowsPer;
  float s = 0.f, ss = 0.f;
  for (int r = 0; r < rowsPer; ++r) {
    size_t idx = (size_t)(r0 + r) * Ncols + c;
    float v = Yp[idx];
    for (int p = 1; p < P; ++p) v += Yp[idx + (size_t)p * pstride];
    Yred[idx] = v;
    s += v;
    ss += v * v;
  }
  psum[(size_t)blockIdx.y * Ncols + c] = s;
  psq[(size_t)blockIdx.y * Ncols + c] = ss;
}

__global__ void bn_finalize_kernel(const float* __restrict__ psum, const float* __restrict__ psq,
                                   const float* __restrict__ g, const float* __restrict__ b,
                                   float* __restrict__ scale, float* __restrict__ shift,
                                   int Ncols, int P, float invM) {
  int c = blockIdx.x * blockDim.x + threadIdx.x;
  if (c >= Ncols) return;
  float s = 0.f, ss = 0.f;
  for (int p = 0; p < P; ++p) {
    s += psum[(size_t)p * Ncols + c];
    ss += psq[(size_t)p * Ncols + c];
  }
  float mean = s * invM;
  float var = ss * invM - mean * mean;
  float rstd = rsqrtf(var + 1e-5f);
  float sc = rstd * g[c];
  scale[c] = sc;
  shift[c] = b[c] - mean * sc;
}

// pass 2: apply, vectorized float4 -> 4x bf16 (FC divisible by 4)
__global__ void bn_apply4_kernel(const float4* __restrict__ Y, const float* __restrict__ scale,
                                 const float* __restrict__ shift, ushort4v* __restrict__ X,
                                 int colGroupsMask, int total4) {
  int i = blockIdx.x * blockDim.x + threadIdx.x;
  if (i >= total4) return;
  int c0 = (i & colGroupsMask) * 4;
  float4 v = Y[i];
  ushort4v o;
  o[0] = f2bf(fmaxf(v.x * scale[c0 + 0] + shift[c0 + 0], 0.0f));
  o[1] = f2bf(fmaxf(v.y * scale[c0 + 1] + shift[c0 + 1], 0.0f));
  o[2] = f2bf(fmaxf(v.z * scale[c0 + 2] + shift[c0 + 2], 0.0f));
  o[3] = f2bf(fmaxf(v.w * scale[c0 + 3] + shift[c0 + 3], 0.0f));
  X[i] = o;
}

// ---------------- decode ----------------
// Y3 holds KSPLIT=4 partials of (2048 x 96)
__global__ void decode_kernel(const float* __restrict__ Y3, const float* __restrict__ pb,
                              const float* __restrict__ anchors, const int* __restrict__ aid,
                              float* __restrict__ out) {
  int i = blockIdx.x * blockDim.x + threadIdx.x;
  if (i >= 2048 * 94) return;
  int bn = i / 94;
  int ch = i - bn * 94;
  size_t idx = (size_t)bn * 96 + ch;
  float v = Y3[idx] + Y3[idx + 2048 * 96] + Y3[idx + 2 * 2048 * 96] + Y3[idx + 3 * 2048 * 96];
  v += pb[ch];
  float o = v;
  if (ch >= 4 && ch < 22) {
    int q = ch - 4;
    int d = q % 6;   // within-class: 0,1=yx 2,3=lw 4,5=zh
    if (d < 2) {
      float stride_px = (float)(8 << (aid[bn] / 3));
      o = anchors[(size_t)bn * 4 + d] + v * stride_px;
    } else if (d < 4) {
      float cl = fminf(fmaxf(v, -4.0f), 4.0f);
      o = anchors[(size_t)bn * 4 + d] * expf(cl);
    }
  }
  out[i] = o;
}

// ---------------- launch ----------------
extern "C" void kernel_launch(void* const* d_in, const int* in_sizes, int n_in,
                              void* d_out, int out_size, void* d_ws, size_t ws_size,
                              hipStream_t stream) {
  const float* feat_p3   = (const float*)d_in[0];
  const float* feat_p4   = (const float*)d_in[1];
  const float* feat_p5   = (const float*)d_in[2];
  const float* bbox2d    = (const float*)d_in[3];
  const float* anchors   = (const float*)d_in[4];
  const int*   anchor_id = (const int*)d_in[5];
  const float* fc1_w     = (const float*)d_in[6];
  // d_in[7] fc1_b: cancels through train-mode BN (mean subtraction) — unused
  const float* bn1_g     = (const float*)d_in[8];
  const float* bn1_b     = (const float*)d_in[9];
  const float* fc2_w     = (const float*)d_in[10];
  // d_in[11] fc2_b: cancels — unused
  const float* bn2_g     = (const float*)d_in[12];
  const float* bn2_b     = (const float*)d_in[13];
  const float* pred_w    = (const float*)d_in[14];
  const float* pred_b    = (const float*)d_in[15];
  float* out = (float*)d_out;

  const int M = 2048;          // B*N
  const int K1 = 12544;        // 256*7*7
  const int FC = 1024;
  const int RG = 128;          // BN stats row-groups

  char* ws = (char*)d_ws;
  auto alloc = [&](size_t bytes) -> char* {
    char* p = ws;
    ws += (bytes + 255) & ~(size_t)255;
    return p;
  };
  unsigned short* W1b  = (unsigned short*)alloc((size_t)FC * K1 * 2);
  unsigned short* W2b  = (unsigned short*)alloc((size_t)FC * FC * 2);
  unsigned short* W3b  = (unsigned short*)alloc((size_t)96 * FC * 2);
  unsigned short* X1   = (unsigned short*)alloc((size_t)M * K1 * 2);
  float*          Yp   = (float*)alloc((size_t)4 * M * FC * 4);  // split-K partials
  float*          Yr   = (float*)alloc((size_t)M * FC * 4);      // reduced Y
  unsigned short* X2   = (unsigned short*)alloc((size_t)M * FC * 2);
  unsigned short* X3   = (unsigned short*)alloc((size_t)M * FC * 2);
  float*          Y3   = (float*)alloc((size_t)4 * M * 96 * 4);
  float*          ps   = (float*)alloc((size_t)RG * FC * 4);
  float*          pq   = (float*)alloc((size_t)RG * FC * 4);
  float*          sc1  = (float*)alloc((size_t)FC * 4);
  float*          sh1  = (float*)alloc((size_t)FC * 4);
  float*          sc2  = (float*)alloc((size_t)FC * 4);
  float*          sh2  = (float*)alloc((size_t)FC * 4);

  // weight conversions (must redo each call — no cross-call state allowed)
  {
    size_t n4 = (size_t)FC * K1 / 4;
    cvt_bf16x4_kernel<<<(unsigned)((n4 + 255) / 256), 256, 0, stream>>>(
        (const float4*)fc1_w, (ushort4v*)W1b, n4);
  }
  {
    size_t n4 = (size_t)FC * FC / 4;
    cvt_bf16x4_kernel<<<(unsigned)((n4 + 255) / 256), 256, 0, stream>>>(
        (const float4*)fc2_w, (ushort4v*)W2b, n4);
  }
  cvt_pad_pred_kernel<<<(96 * 1024) / 256, 256, 0, stream>>>(pred_w, W3b);

  // ROI align (fused, hoisted B-invariants) -> X1 (2048 x 12544) bf16
  roi_mm5_kernel<<<dim3(2048, 8), 256, 0, stream>>>(feat_p3, feat_p4, feat_p5,
                                                    bbox2d, anchor_id, X1);

  // fc1: X1 (2048x12544) @ W1^T -> Yp (4 partials of 2048x1024)
  gemm_bt_swz<4><<<dim3(M / 128, FC / 128, 4), 256, 0, stream>>>(X1, W1b, Yp, M, FC, K1);

  // BN1: reduce partials + stats (512 blocks), finalize, apply+ReLU -> X2 bf16
  bn_stats_red_kernel<<<dim3(FC / 256, RG), 256, 0, stream>>>(Yp, Yr, ps, pq, FC, M / RG, 4, (size_t)M * FC);
  bn_finalize_kernel<<<FC / 256, 256, 0, stream>>>(ps, pq, bn1_g, bn1_b, sc1, sh1, FC, RG, 1.0f / M);
  bn_apply4_kernel<<<(M * FC / 4) / 256, 256, 0, stream>>>(
      (const float4*)Yr, sc1, sh1, (ushort4v*)X2, FC / 4 - 1, M * FC / 4);

  // fc2: X2 @ W2^T -> Yp (2 partials)
  gemm_bt_swz<2><<<dim3(M / 128, FC / 128, 2), 256, 0, stream>>>(X2, W2b, Yp, M, FC, FC);

  // BN2 + ReLU -> X3 bf16
  bn_stats_red_kernel<<<dim3(FC / 256, RG), 256, 0, stream>>>(Yp, Yr, ps, pq, FC, M / RG, 2, (size_t)M * FC);
  bn_finalize_kernel<<<FC / 256, 256, 0, stream>>>(ps, pq, bn2_g, bn2_b, sc2, sh2, FC, RG, 1.0f / M);
  bn_apply4_kernel<<<(M * FC / 4) / 256, 256, 0, stream>>>(
      (const float4*)Yr, sc2, sh2, (ushort4v*)X3, FC / 4 - 1, M * FC / 4);

  // pred head: X3 @ W3p^T -> Y3 (split-K=4 partials of 2048 x 96)
  gemm_bt_kernel<64, 96, 2, 2, 4><<<dim3(M / 64, 1, 4), 256, 0, stream>>>(X3, W3b, Y3, M, 96, FC);

  // decode -> out (2048 x 94)
  decode_kernel<<<(2048 * 94 + 255) / 256, 256, 0, stream>>>(Y3, pred_b, anchors, anchor_id, out);
}

// Round 12
// 257.017 us; speedup vs baseline: 1.2606x; 1.0090x over previous
//
#include <hip/hip_runtime.h>
#include <hip/hip_bf16.h>

typedef __attribute__((ext_vector_type(8))) short short8;
typedef __attribute__((ext_vector_type(4))) float floatx4;
typedef __attribute__((ext_vector_type(4))) unsigned short ushort4v;

#define DEVI __device__ __forceinline__

// ---------------- constants ----------------
// B=4, N=512, C_IN=256, RES=7, SR=2, FC_DIM=1024, OUT_CH=94
// M = B*N = 2048 rows, K1 = 256*7*7 = 12544

DEVI unsigned short f2bf(float v) {
  union { __hip_bfloat16 h; unsigned short u; } cv;
  cv.h = __float2bfloat16(v);
  return cv.u;
}
DEVI short f2bfs(float v) { return (short)f2bf(v); }

DEVI void gload16(const void* gptr, void* lptr) {
  __builtin_amdgcn_global_load_lds(
      (const __attribute__((address_space(1))) unsigned int*)gptr,
      (__attribute__((address_space(3))) unsigned int*)(unsigned long long)(uintptr_t)lptr,
      16, 0, 0);
}

// ---------------- weight conversion (vectorized: 4 floats -> 4 bf16 / thread) ----------------
__global__ void cvt_bf16x4_kernel(const float4* __restrict__ src,
                                  ushort4v* __restrict__ dst, size_t n4) {
  size_t i = (size_t)blockIdx.x * blockDim.x + threadIdx.x;
  if (i >= n4) return;
  float4 v = src[i];
  ushort4v o;
  o[0] = f2bf(v.x); o[1] = f2bf(v.y); o[2] = f2bf(v.z); o[3] = f2bf(v.w);
  dst[i] = o;
}

// pred_w (94x1024) -> padded (96x1024) bf16, rows 94..95 zero
__global__ void cvt_pad_pred_kernel(const float* __restrict__ src,
                                    unsigned short* __restrict__ dst) {
  int i = blockIdx.x * blockDim.x + threadIdx.x;
  if (i >= 96 * 1024) return;
  int row = i >> 10;
  dst[i] = (row < 94) ? f2bf(src[i]) : (unsigned short)0;
}

// ---------------- ROI align v9 (roi_mm6): cvt-once in-place + conflict-optimal Pb ----------------
// Out[ch][cell] = sum_{r,c} P[ch][r*16+c] * wy[py][r] * wx[px][c].
// P staged f32 via global_load_lds (R7 path). Then ONE cooperative pass:
// each thread captures its own 32 f32 to regs, barrier, writes packed bf16 into
// Pb OVERLAYING Pf (dead after capture) with row stride 280 shorts (560 B) ->
// hot-loop ds_read_b128 lands exactly 8 dwords/bank (optimal). Hot loop:
// 2x ds_read_b128 + reg-B build (8 mul + 8 cvt) + 2 MFMA per kk.
// LDS 34.5 KB -> 4 blocks/CU. grid (2048 boxes, 8 channel-octets of 32).
__global__ __launch_bounds__(256) void roi_mm6_kernel(
    const float* __restrict__ p3, const float* __restrict__ p4,
    const float* __restrict__ p5, const float* __restrict__ bbox,
    const int* __restrict__ aid, unsigned short* __restrict__ X) {
  constexpr int PS = 260;   // f32 per-channel stride (staging layout)
  constexpr int PBS = 280;  // bf16 per-channel stride (hot-loop layout, 560 B)
  __shared__ float Pf[32 * PS];            // 33280 B; Pb (17920 B) overlays it
  __shared__ float wyx[238];               // wy [7][17] @0, wx [7][17] @119
  __shared__ int sy0[14], sx0[14];
  __shared__ float sly[14], slx[14];
  unsigned short* Pb = (unsigned short*)Pf;

  const int box = blockIdx.x;
  const int oct = blockIdx.y;              // channels oct*32 ..
  const int b = box >> 9;
  const int tid = threadIdx.x;
  const int lane = tid & 63, wid = tid >> 6;

  const int lvl = aid[box] / 3;
  const int H = 64 >> lvl;
  const int HH = H * H;
  const float* base = (lvl == 0) ? p3 : ((lvl == 1) ? p4 : p5);
  const float scale = 0.125f / (float)(1 << lvl);

  // ---- phase A: sample grid ----
  if (tid < 28) {
    int s = tid;
    bool isY = s < 14;
    int k = isY ? s : s - 14;
    float lo = bbox[box * 4 + (isY ? 0 : 1)];
    float hi = bbox[box * 4 + (isY ? 2 : 3)];
    float t = lo * scale - 0.5f;
    float cell = (hi - lo) * scale * (1.0f / 7.0f);
    float pos = t + ((float)k + 0.5f) * 0.5f * cell;   // S=14 samples, SR=2
    pos = fminf(fmaxf(pos, 0.0f), (float)(H - 1));
    int i0 = (int)floorf(pos);
    if (i0 > H - 2) i0 = H - 2;        // fr=1 reproduces the clamp
    float fr = pos - (float)i0;
    if (isY) { sy0[k] = i0; sly[k] = fr; }
    else     { sx0[k] = i0; slx[k] = fr; }
  }
  __syncthreads();

  const int ryb = min(sy0[0], H - 16);   // monotone grid -> sy0[0]/sx0[0] are minima
  const int rxb = min(sx0[0], H - 16);
  const float* fb = base + ((size_t)b * 256 + oct * 32) * HH + ryb * H + rxb;

  // ---- phase B1: separable pooled weights wy[7][16], wx[7][16] (stride 17) ----
  if (tid < 224) {
    int j = tid;
    bool isY = j < 112;
    int k2 = isY ? j : j - 112;
    int py = k2 >> 4, r = k2 & 15;
    int o0 = isY ? ryb : rxb;
    float acc = 0.f;
#pragma unroll
    for (int ss = 0; ss < 2; ++ss) {
      int s = 2 * py + ss;
      int rel = (isY ? sy0[s] : sx0[s]) - o0;
      float fr = isY ? sly[s] : slx[s];
      if (r == rel)     acc += 1.0f - fr;
      if (r == rel + 1) acc += fr;
    }
    wyx[(isY ? 0 : 119) + py * 17 + r] = acc * 0.5f;
  }

  // ---- phase B2: stage P f32 via global_load_lds (1 wave-op = 1 channel's 1KB patch) ----
  {
    const int r = lane >> 2, c4 = (lane & 3) * 4;
    const float* src0 = fb + r * H + c4;
#pragma unroll
    for (int it = 0; it < 8; ++it) {
      int ch = it * 4 + wid;
      gload16(src0 + (size_t)ch * HH, &Pf[ch * PS] + lane * 4);
    }
  }
  __syncthreads();   // gload16 drained; wyx ready

  // ---- phase B3: cvt-once, in place. thread: ch = tid&31, row-pair rp = tid>>5 ----
  {
    const int cch = tid & 31, rp = tid >> 5;
    const float* src = &Pf[cch * PS + rp * 32];
    floatx4 v[8];
#pragma unroll
    for (int m = 0; m < 8; ++m) v[m] = *(const floatx4*)(src + 4 * m);
    __syncthreads();                       // all captures done before overwrite
    unsigned int d[16];
#pragma unroll
    for (int m = 0; m < 8; ++m) {
      d[2 * m]     = (unsigned int)f2bf(v[m][0]) | ((unsigned int)f2bf(v[m][1]) << 16);
      d[2 * m + 1] = (unsigned int)f2bf(v[m][2]) | ((unsigned int)f2bf(v[m][3]) << 16);
    }
    unsigned short* dst = &Pb[cch * PBS + rp * 32];
#pragma unroll
    for (int m = 0; m < 4; ++m)
      *(uint4*)(dst + m * 8) = make_uint4(d[4 * m], d[4 * m + 1], d[4 * m + 2], d[4 * m + 3]);
  }

  // hoist B invariants while cvt settles: x-slice (kk-invariant) and wy stride-2 sequence
  const int fr = lane & 15, fg = lane >> 4;
  const int cell = wid * 16 + fr;          // 0..63; valid < 49
  const int py = (cell * 37) >> 8;         // cell/7 for 0..63 (py<=9: garbage reads, masked)
  const int px = cell - py * 7;
  float xv[8], wyv[8];
  {
    const float* xp = &wyx[119 + px * 17 + (fg & 1) * 8];
#pragma unroll
    for (int e = 0; e < 8; ++e) xv[e] = xp[e];
    const float* wp = &wyx[py * 17 + (fg >> 1)];
#pragma unroll
    for (int kk = 0; kk < 8; ++kk) wyv[kk] = wp[2 * kk];
  }
  __syncthreads();                         // Pb fully written

  // ---- phase C: MFMA hot loop — 2x ds_read_b128 + reg-B + 2 MFMA per kk ----
  floatx4 acc0 = (floatx4){0.f, 0.f, 0.f, 0.f};   // channels 0..15
  floatx4 acc1 = (floatx4){0.f, 0.f, 0.f, 0.f};   // channels 16..31

#pragma unroll
  for (int kk = 0; kk < 8; ++kk) {
    short8 af0 = *(const short8*)&Pb[fr * PBS + kk * 32 + fg * 8];
    short8 af1 = *(const short8*)&Pb[(16 + fr) * PBS + kk * 32 + fg * 8];
    short8 bfr;
    const float w = wyv[kk];
#pragma unroll
    for (int e = 0; e < 8; ++e) bfr[e] = f2bfs(w * xv[e]);
    acc0 = __builtin_amdgcn_mfma_f32_16x16x32_bf16(af0, bfr, acc0, 0, 0, 0);
    acc1 = __builtin_amdgcn_mfma_f32_16x16x32_bf16(af1, bfr, acc1, 0, 0, 0);
  }

  if (cell < 49) {
    unsigned short* xb = X + (size_t)box * 12544 + (size_t)(oct * 32) * 49 + cell;
#pragma unroll
    for (int q = 0; q < 4; ++q) {
      xb[(fg * 4 + q) * 49] = f2bf(acc0[q]);
      xb[(16 + fg * 4 + q) * 49] = f2bf(acc1[q]);
    }
  }
}

// ---------------- GEMM v2: 128x128 tile, BK=64, T2 XOR-swizzle, split-K ----------------
template <int KSPLIT>
__global__ __launch_bounds__(256) void gemm_bt_swz(
    const unsigned short* __restrict__ A, const unsigned short* __restrict__ Bw,
    float* __restrict__ C, int M, int N, int K) {
  constexpr int BM = 128, BN = 128, BK = 64;
  __shared__ unsigned short As[BM * BK];   // 16 KB
  __shared__ unsigned short Bs[BN * BK];   // 16 KB

  const int tid = threadIdx.x;
  const int lane = tid & 63, wid = tid >> 6;
  const int wr = wid >> 1, wc = wid & 1;    // 2x2 waves, 64x64 each
  const int tm = blockIdx.x * BM, tn = blockIdx.y * BN;
  const int fr = lane & 15, fg = lane >> 4;

  const int kLen = K / KSPLIT;
  const int kTiles = kLen / BK;
  const int kBeg = blockIdx.z * kLen;
  float* Cz = C + (size_t)blockIdx.z * M * N;

  floatx4 acc[4][4];
#pragma unroll
  for (int i = 0; i < 4; ++i)
#pragma unroll
    for (int j = 0; j < 4; ++j)
      acc[i][j] = (floatx4){0.f, 0.f, 0.f, 0.f};

  for (int t = 0; t < kTiles; ++t) {
    const int k0 = kBeg + t * BK;
#pragma unroll
    for (int s = tid; s < BM * 8; s += 256) {
      int row = s >> 3, sl = s & 7;
      int slg = sl ^ (row & 7);
      gload16(&A[(size_t)(tm + row) * K + k0 + slg * 8], &As[s * 8]);
    }
#pragma unroll
    for (int s = tid; s < BN * 8; s += 256) {
      int row = s >> 3, sl = s & 7;
      int slg = sl ^ (row & 7);
      gload16(&Bw[(size_t)(tn + row) * K + k0 + slg * 8], &Bs[s * 8]);
    }
    __syncthreads();

#pragma unroll
    for (int kk = 0; kk < 2; ++kk) {
      short8 af[4], bf[4];
#pragma unroll
      for (int i = 0; i < 4; ++i) {
        int row = wr * 64 + i * 16 + fr;
        int sl = (kk * 4 + fg) ^ (row & 7);
        af[i] = *reinterpret_cast<const short8*>(&As[(row * 8 + sl) * 8]);
      }
#pragma unroll
      for (int j = 0; j < 4; ++j) {
        int row = wc * 64 + j * 16 + fr;
        int sl = (kk * 4 + fg) ^ (row & 7);
        bf[j] = *reinterpret_cast<const short8*>(&Bs[(row * 8 + sl) * 8]);
      }
#pragma unroll
      for (int i = 0; i < 4; ++i)
#pragma unroll
        for (int j = 0; j < 4; ++j)
          acc[i][j] = __builtin_amdgcn_mfma_f32_16x16x32_bf16(af[i], bf[j], acc[i][j], 0, 0, 0);
    }
    __syncthreads();
  }

#pragma unroll
  for (int i = 0; i < 4; ++i)
#pragma unroll
    for (int j = 0; j < 4; ++j)
#pragma unroll
      for (int q = 0; q < 4; ++q) {
        int rr = tm + wr * 64 + i * 16 + fg * 4 + q;
        int cc = tn + wc * 64 + j * 16 + fr;
        Cz[(size_t)rr * N + cc] = acc[i][j][q];
      }
}

// ---------------- old GEMM (pred head only) ----------------
template <int BM, int BN, int WAVES_M, int WAVES_N, int KSPLIT>
__global__ __launch_bounds__(256) void gemm_bt_kernel(
    const unsigned short* __restrict__ A, const unsigned short* __restrict__ Bw,
    float* __restrict__ C, int M, int N, int K) {
  constexpr int BK = 32;
  constexpr int WM = BM / WAVES_M, WN = BN / WAVES_N;
  constexpr int AF = WM / 16, BF = WN / 16;
  constexpr int ASLOT = BM * 4;
  constexpr int BSLOT = BN * 4;
  __shared__ unsigned short As[BM * BK];
  __shared__ unsigned short Bs[BN * BK];

  const int tid = threadIdx.x;
  const int lane = tid & 63, wid = tid >> 6;
  const int wr = wid / WAVES_N, wc = wid % WAVES_N;
  const int tm = blockIdx.x * BM, tn = blockIdx.y * BN;
  const int fr = lane & 15, fg = lane >> 4;

  const int kLen = K / KSPLIT;
  const int kBeg = blockIdx.z * kLen;
  float* Cz = C + (size_t)blockIdx.z * M * N;

  floatx4 acc[AF][BF];
#pragma unroll
  for (int i = 0; i < AF; ++i)
#pragma unroll
    for (int j = 0; j < BF; ++j)
      acc[i][j] = (floatx4){0.f, 0.f, 0.f, 0.f};

  for (int k0 = kBeg; k0 < kBeg + kLen; k0 += BK) {
#pragma unroll
    for (int s = tid; s < ASLOT; s += 256) {
      int row = s >> 2, kb = (s & 3) << 3;
      gload16(&A[(size_t)(tm + row) * K + k0 + kb], &As[s * 8]);
    }
#pragma unroll
    for (int s = tid; s < BSLOT; s += 256) {
      int row = s >> 2, kb = (s & 3) << 3;
      gload16(&Bw[(size_t)(tn + row) * K + k0 + kb], &Bs[s * 8]);
    }
    __syncthreads();

    short8 af[AF], bfv[BF];
#pragma unroll
    for (int i = 0; i < AF; ++i)
      af[i] = *reinterpret_cast<const short8*>(&As[(wr * WM + i * 16 + fr) * BK + fg * 8]);
#pragma unroll
    for (int j = 0; j < BF; ++j)
      bfv[j] = *reinterpret_cast<const short8*>(&Bs[(wc * WN + j * 16 + fr) * BK + fg * 8]);
#pragma unroll
    for (int i = 0; i < AF; ++i)
#pragma unroll
      for (int j = 0; j < BF; ++j)
        acc[i][j] = __builtin_amdgcn_mfma_f32_16x16x32_bf16(af[i], bfv[j], acc[i][j], 0, 0, 0);
    __syncthreads();
  }

#pragma unroll
  for (int i = 0; i < AF; ++i)
#pragma unroll
    for (int j = 0; j < BF; ++j)
#pragma unroll
      for (int q = 0; q < 4; ++q) {
        int rr = tm + wr * WM + i * 16 + fg * 4 + q;
        int cc = tn + wc * WN + j * 16 + fr;
        Cz[(size_t)rr * N + cc] = acc[i][j][q];
      }
}

// ---------------- BatchNorm (train mode) ----------------
// pass 1: reduce split-K partials + per-rowgroup stats. grid (Ncols/256, 128).
__global__ void bn_stats_red_kernel(const float* __restrict__ Yp, float* __restrict__ Yred,
                                    float* __restrict__ psum, float* __restrict__ psq,
                                    int Ncols, int rowsPer, int P, size_t pstride) {
  int c = blockIdx.x * blockDim.x + threadIdx.x;
  int r0 = blockIdx.y * rowsPer;
  float s = 0.f, ss = 0.f;
  for (int r = 0; r < rowsPer; ++r) {
    size_t idx = (size_t)(r0 + r) * Ncols + c;
    float v = Yp[idx];
    for (int p = 1; p < P; ++p) v += Yp[idx + (size_t)p * pstride];
    Yred[idx] = v;
    s += v;
    ss += v * v;
  }
  psum[(size_t)blockIdx.y * Ncols + c] = s;
  psq[(size_t)blockIdx.y * Ncols + c] = ss;
}

__global__ void bn_finalize_kernel(const float* __restrict__ psum, const float* __restrict__ psq,
                                   const float* __restrict__ g, const float* __restrict__ b,
                                   float* __restrict__ scale, float* __restrict__ shift,
                                   int Ncols, int P, float invM) {
  int c = blockIdx.x * blockDim.x + threadIdx.x;
  if (c >= Ncols) return;
  float s = 0.f, ss = 0.f;
  for (int p = 0; p < P; ++p) {
    s += psum[(size_t)p * Ncols + c];
    ss += psq[(size_t)p * Ncols + c];
  }
  float mean = s * invM;
  float var = ss * invM - mean * mean;
  float rstd = rsqrtf(var + 1e-5f);
  float sc = rstd * g[c];
  scale[c] = sc;
  shift[c] = b[c] - mean * sc;
}

// pass 2: apply, vectorized float4 -> 4x bf16 (FC divisible by 4)
__global__ void bn_apply4_kernel(const float4* __restrict__ Y, const float* __restrict__ scale,
                                 const float* __restrict__ shift, ushort4v* __restrict__ X,
                                 int colGroupsMask, int total4) {
  int i = blockIdx.x * blockDim.x + threadIdx.x;
  if (i >= total4) return;
  int c0 = (i & colGroupsMask) * 4;
  float4 v = Y[i];
  ushort4v o;
  o[0] = f2bf(fmaxf(v.x * scale[c0 + 0] + shift[c0 + 0], 0.0f));
  o[1] = f2bf(fmaxf(v.y * scale[c0 + 1] + shift[c0 + 1], 0.0f));
  o[2] = f2bf(fmaxf(v.z * scale[c0 + 2] + shift[c0 + 2], 0.0f));
  o[3] = f2bf(fmaxf(v.w * scale[c0 + 3] + shift[c0 + 3], 0.0f));
  X[i] = o;
}

// ---------------- decode ----------------
// Y3 holds KSPLIT=4 partials of (2048 x 96)
__global__ void decode_kernel(const float* __restrict__ Y3, const float* __restrict__ pb,
                              const float* __restrict__ anchors, const int* __restrict__ aid,
                              float* __restrict__ out) {
  int i = blockIdx.x * blockDim.x + threadIdx.x;
  if (i >= 2048 * 94) return;
  int bn = i / 94;
  int ch = i - bn * 94;
  size_t idx = (size_t)bn * 96 + ch;
  float v = Y3[idx] + Y3[idx + 2048 * 96] + Y3[idx + 2 * 2048 * 96] + Y3[idx + 3 * 2048 * 96];
  v += pb[ch];
  float o = v;
  if (ch >= 4 && ch < 22) {
    int q = ch - 4;
    int d = q % 6;   // within-class: 0,1=yx 2,3=lw 4,5=zh
    if (d < 2) {
      float stride_px = (float)(8 << (aid[bn] / 3));
      o = anchors[(size_t)bn * 4 + d] + v * stride_px;
    } else if (d < 4) {
      float cl = fminf(fmaxf(v, -4.0f), 4.0f);
      o = anchors[(size_t)bn * 4 + d] * expf(cl);
    }
  }
  out[i] = o;
}

// ---------------- launch ----------------
extern "C" void kernel_launch(void* const* d_in, const int* in_sizes, int n_in,
                              void* d_out, int out_size, void* d_ws, size_t ws_size,
                              hipStream_t stream) {
  const float* feat_p3   = (const float*)d_in[0];
  const float* feat_p4   = (const float*)d_in[1];
  const float* feat_p5   = (const float*)d_in[2];
  const float* bbox2d    = (const float*)d_in[3];
  const float* anchors   = (const float*)d_in[4];
  const int*   anchor_id = (const int*)d_in[5];
  const float* fc1_w     = (const float*)d_in[6];
  // d_in[7] fc1_b: cancels through train-mode BN (mean subtraction) — unused
  const float* bn1_g     = (const float*)d_in[8];
  const float* bn1_b     = (const float*)d_in[9];
  const float* fc2_w     = (const float*)d_in[10];
  // d_in[11] fc2_b: cancels — unused
  const float* bn2_g     = (const float*)d_in[12];
  const float* bn2_b     = (const float*)d_in[13];
  const float* pred_w    = (const float*)d_in[14];
  const float* pred_b    = (const float*)d_in[15];
  float* out = (float*)d_out;

  const int M = 2048;          // B*N
  const int K1 = 12544;        // 256*7*7
  const int FC = 1024;
  const int RG = 128;          // BN stats row-groups

  char* ws = (char*)d_ws;
  auto alloc = [&](size_t bytes) -> char* {
    char* p = ws;
    ws += (bytes + 255) & ~(size_t)255;
    return p;
  };
  unsigned short* W1b  = (unsigned short*)alloc((size_t)FC * K1 * 2);
  unsigned short* W2b  = (unsigned short*)alloc((size_t)FC * FC * 2);
  unsigned short* W3b  = (unsigned short*)alloc((size_t)96 * FC * 2);
  unsigned short* X1   = (unsigned short*)alloc((size_t)M * K1 * 2);
  float*          Yp   = (float*)alloc((size_t)4 * M * FC * 4);  // split-K partials
  float*          Yr   = (float*)alloc((size_t)M * FC * 4);      // reduced Y
  unsigned short* X2   = (unsigned short*)alloc((size_t)M * FC * 2);
  unsigned short* X3   = (unsigned short*)alloc((size_t)M * FC * 2);
  float*          Y3   = (float*)alloc((size_t)4 * M * 96 * 4);
  float*          ps   = (float*)alloc((size_t)RG * FC * 4);
  float*          pq   = (float*)alloc((size_t)RG * FC * 4);
  float*          sc1  = (float*)alloc((size_t)FC * 4);
  float*          sh1  = (float*)alloc((size_t)FC * 4);
  float*          sc2  = (float*)alloc((size_t)FC * 4);
  float*          sh2  = (float*)alloc((size_t)FC * 4);

  // weight conversions (must redo each call — no cross-call state allowed)
  {
    size_t n4 = (size_t)FC * K1 / 4;
    cvt_bf16x4_kernel<<<(unsigned)((n4 + 255) / 256), 256, 0, stream>>>(
        (const float4*)fc1_w, (ushort4v*)W1b, n4);
  }
  {
    size_t n4 = (size_t)FC * FC / 4;
    cvt_bf16x4_kernel<<<(unsigned)((n4 + 255) / 256), 256, 0, stream>>>(
        (const float4*)fc2_w, (ushort4v*)W2b, n4);
  }
  cvt_pad_pred_kernel<<<(96 * 1024) / 256, 256, 0, stream>>>(pred_w, W3b);

  // ROI align (fused, cvt-once in-place) -> X1 (2048 x 12544) bf16
  roi_mm6_kernel<<<dim3(2048, 8), 256, 0, stream>>>(feat_p3, feat_p4, feat_p5,
                                                    bbox2d, anchor_id, X1);

  // fc1: X1 (2048x12544) @ W1^T -> Yp (4 partials of 2048x1024)
  gemm_bt_swz<4><<<dim3(M / 128, FC / 128, 4), 256, 0, stream>>>(X1, W1b, Yp, M, FC, K1);

  // BN1: reduce partials + stats (512 blocks), finalize, apply+ReLU -> X2 bf16
  bn_stats_red_kernel<<<dim3(FC / 256, RG), 256, 0, stream>>>(Yp, Yr, ps, pq, FC, M / RG, 4, (size_t)M * FC);
  bn_finalize_kernel<<<FC / 256, 256, 0, stream>>>(ps, pq, bn1_g, bn1_b, sc1, sh1, FC, RG, 1.0f / M);
  bn_apply4_kernel<<<(M * FC / 4) / 256, 256, 0, stream>>>(
      (const float4*)Yr, sc1, sh1, (ushort4v*)X2, FC / 4 - 1, M * FC / 4);

  // fc2: X2 @ W2^T -> Yp (2 partials)
  gemm_bt_swz<2><<<dim3(M / 128, FC / 128, 2), 256, 0, stream>>>(X2, W2b, Yp, M, FC, FC);

  // BN2 + ReLU -> X3 bf16
  bn_stats_red_kernel<<<dim3(FC / 256, RG), 256, 0, stream>>>(Yp, Yr, ps, pq, FC, M / RG, 2, (size_t)M * FC);
  bn_finalize_kernel<<<FC / 256, 256, 0, stream>>>(ps, pq, bn2_g, bn2_b, sc2, sh2, FC, RG, 1.0f / M);
  bn_apply4_kernel<<<(M * FC / 4) / 256, 256, 0, stream>>>(
      (const float4*)Yr, sc2, sh2, (ushort4v*)X3, FC / 4 - 1, M * FC / 4);

  // pred head: X3 @ W3p^T -> Y3 (split-K=4 partials of 2048 x 96)
  gemm_bt_kernel<64, 96, 2, 2, 4><<<dim3(M / 64, 1, 4), 256, 0, stream>>>(X3, W3b, Y3, M, 96, FC);

  // decode -> out (2048 x 94)
  decode_kernel<<<(2048 * 94 + 255) / 256, 256, 0, stream>>>(Y3, pred_b, anchors, anchor_id, out);
}

// Round 13
// 251.089 us; speedup vs baseline: 1.2904x; 1.0236x over previous
//
#include <hip/hip_runtime.h>
#include <hip/hip_bf16.h>

typedef __attribute__((ext_vector_type(8))) short short8;
typedef __attribute__((ext_vector_type(4))) float floatx4;
typedef __attribute__((ext_vector_type(4))) unsigned short ushort4v;

#define DEVI __device__ __forceinline__

// ---------------- constants ----------------
// B=4, N=512, C_IN=256, RES=7, SR=2, FC_DIM=1024, OUT_CH=94
// M = B*N = 2048 rows, K1 = 256*7*7 = 12544

DEVI unsigned short f2bf(float v) {
  union { __hip_bfloat16 h; unsigned short u; } cv;
  cv.h = __float2bfloat16(v);
  return cv.u;
}
DEVI short f2bfs(float v) { return (short)f2bf(v); }

DEVI void gload16(const void* gptr, void* lptr) {
  __builtin_amdgcn_global_load_lds(
      (const __attribute__((address_space(1))) unsigned int*)gptr,
      (__attribute__((address_space(3))) unsigned int*)(unsigned long long)(uintptr_t)lptr,
      16, 0, 0);
}

// ---------------- fused prep + ROI align ----------------
// Block ranges (uniform branch per block):
//   [0, 16384)          : ROI align (roi_mm6 body), box = bid&2047, oct = bid>>11
//   [16384, 28928)      : cvt fc1_w f32->bf16 (12544 blocks, 4 elems/thread)
//   [28928, 29952)      : cvt fc2_w f32->bf16 (1024 blocks)
//   [29952, 30336)      : pred_w pad-cvt (384 blocks)
// The BW-bound cvt blocks overlap the latency-bound roi blocks.
#define ROI_BLKS   16384
#define CVT1_END   28928
#define CVT2_END   29952
#define GRID_TOTAL 30336

__global__ __launch_bounds__(256) void prep_roi_kernel(
    const float* __restrict__ p3, const float* __restrict__ p4,
    const float* __restrict__ p5, const float* __restrict__ bbox,
    const int* __restrict__ aid, unsigned short* __restrict__ X,
    const float* __restrict__ fc1_w, unsigned short* __restrict__ W1b,
    const float* __restrict__ fc2_w, unsigned short* __restrict__ W2b,
    const float* __restrict__ pred_w, unsigned short* __restrict__ W3b) {
  constexpr int PS = 260;   // f32 per-channel stride (staging layout)
  constexpr int PBS = 280;  // bf16 per-channel stride (hot-loop layout, 560 B)
  __shared__ float Pf[32 * PS];            // 33280 B; Pb (17920 B) overlays it
  __shared__ float wyx[238];               // wy [7][17] @0, wx [7][17] @119
  __shared__ int sy0[14], sx0[14];
  __shared__ float sly[14], slx[14];

  const int bid = blockIdx.x;
  const int tid = threadIdx.x;

  if (bid >= ROI_BLKS) {
    if (bid < CVT1_END) {
      size_t i = (size_t)(bid - ROI_BLKS) * 256 + tid;   // < 3211264 exactly
      float4 v = ((const float4*)fc1_w)[i];
      ushort4v o;
      o[0] = f2bf(v.x); o[1] = f2bf(v.y); o[2] = f2bf(v.z); o[3] = f2bf(v.w);
      ((ushort4v*)W1b)[i] = o;
    } else if (bid < CVT2_END) {
      size_t i = (size_t)(bid - CVT1_END) * 256 + tid;   // < 262144 exactly
      float4 v = ((const float4*)fc2_w)[i];
      ushort4v o;
      o[0] = f2bf(v.x); o[1] = f2bf(v.y); o[2] = f2bf(v.z); o[3] = f2bf(v.w);
      ((ushort4v*)W2b)[i] = o;
    } else {
      int i = (bid - CVT2_END) * 256 + tid;              // < 98304 exactly
      int row = i >> 10;
      W3b[i] = (row < 94) ? f2bf(pred_w[i]) : (unsigned short)0;
    }
    return;
  }

  // ---------------- ROI branch (roi_mm6 body) ----------------
  unsigned short* Pb = (unsigned short*)Pf;
  const int box = bid & 2047;
  const int oct = bid >> 11;               // channels oct*32 ..
  const int b = box >> 9;
  const int lane = tid & 63, wid = tid >> 6;

  const int lvl = aid[box] / 3;
  const int H = 64 >> lvl;
  const int HH = H * H;
  const float* base = (lvl == 0) ? p3 : ((lvl == 1) ? p4 : p5);
  const float scale = 0.125f / (float)(1 << lvl);

  // ---- phase A: sample grid ----
  if (tid < 28) {
    int s = tid;
    bool isY = s < 14;
    int k = isY ? s : s - 14;
    float lo = bbox[box * 4 + (isY ? 0 : 1)];
    float hi = bbox[box * 4 + (isY ? 2 : 3)];
    float t = lo * scale - 0.5f;
    float cell = (hi - lo) * scale * (1.0f / 7.0f);
    float pos = t + ((float)k + 0.5f) * 0.5f * cell;   // S=14 samples, SR=2
    pos = fminf(fmaxf(pos, 0.0f), (float)(H - 1));
    int i0 = (int)floorf(pos);
    if (i0 > H - 2) i0 = H - 2;        // fr=1 reproduces the clamp
    float fr = pos - (float)i0;
    if (isY) { sy0[k] = i0; sly[k] = fr; }
    else     { sx0[k] = i0; slx[k] = fr; }
  }
  __syncthreads();

  const int ryb = min(sy0[0], H - 16);   // monotone grid -> sy0[0]/sx0[0] are minima
  const int rxb = min(sx0[0], H - 16);
  const float* fb = base + ((size_t)b * 256 + oct * 32) * HH + ryb * H + rxb;

  // ---- phase B1: separable pooled weights wy[7][16], wx[7][16] (stride 17) ----
  if (tid < 224) {
    int j = tid;
    bool isY = j < 112;
    int k2 = isY ? j : j - 112;
    int py = k2 >> 4, r = k2 & 15;
    int o0 = isY ? ryb : rxb;
    float acc = 0.f;
#pragma unroll
    for (int ss = 0; ss < 2; ++ss) {
      int s = 2 * py + ss;
      int rel = (isY ? sy0[s] : sx0[s]) - o0;
      float fr = isY ? sly[s] : slx[s];
      if (r == rel)     acc += 1.0f - fr;
      if (r == rel + 1) acc += fr;
    }
    wyx[(isY ? 0 : 119) + py * 17 + r] = acc * 0.5f;
  }

  // ---- phase B2: stage P f32 via global_load_lds (1 wave-op = 1 channel's 1KB patch) ----
  {
    const int r = lane >> 2, c4 = (lane & 3) * 4;
    const float* src0 = fb + r * H + c4;
#pragma unroll
    for (int it = 0; it < 8; ++it) {
      int ch = it * 4 + wid;
      gload16(src0 + (size_t)ch * HH, &Pf[ch * PS] + lane * 4);
    }
  }
  __syncthreads();   // gload16 drained; wyx ready

  // ---- phase B3: cvt-once, in place. thread: ch = tid&31, row-pair rp = tid>>5 ----
  {
    const int cch = tid & 31, rp = tid >> 5;
    const float* src = &Pf[cch * PS + rp * 32];
    floatx4 v[8];
#pragma unroll
    for (int m = 0; m < 8; ++m) v[m] = *(const floatx4*)(src + 4 * m);
    __syncthreads();                       // all captures done before overwrite
    unsigned int d[16];
#pragma unroll
    for (int m = 0; m < 8; ++m) {
      d[2 * m]     = (unsigned int)f2bf(v[m][0]) | ((unsigned int)f2bf(v[m][1]) << 16);
      d[2 * m + 1] = (unsigned int)f2bf(v[m][2]) | ((unsigned int)f2bf(v[m][3]) << 16);
    }
    unsigned short* dst = &Pb[cch * PBS + rp * 32];
#pragma unroll
    for (int m = 0; m < 4; ++m)
      *(uint4*)(dst + m * 8) = make_uint4(d[4 * m], d[4 * m + 1], d[4 * m + 2], d[4 * m + 3]);
  }

  // hoist B invariants: x-slice (kk-invariant) and wy stride-2 sequence
  const int fr = lane & 15, fg = lane >> 4;
  const int cell = wid * 16 + fr;          // 0..63; valid < 49
  const int py = (cell * 37) >> 8;         // cell/7 for 0..63 (py<=9: garbage reads, masked)
  const int px = cell - py * 7;
  float xv[8], wyv[8];
  {
    const float* xp = &wyx[119 + px * 17 + (fg & 1) * 8];
#pragma unroll
    for (int e = 0; e < 8; ++e) xv[e] = xp[e];
    const float* wp = &wyx[py * 17 + (fg >> 1)];
#pragma unroll
    for (int kk = 0; kk < 8; ++kk) wyv[kk] = wp[2 * kk];
  }
  __syncthreads();                         // Pb fully written

  // ---- phase C: MFMA hot loop — 2x ds_read_b128 + reg-B + 2 MFMA per kk ----
  floatx4 acc0 = (floatx4){0.f, 0.f, 0.f, 0.f};   // channels 0..15
  floatx4 acc1 = (floatx4){0.f, 0.f, 0.f, 0.f};   // channels 16..31

#pragma unroll
  for (int kk = 0; kk < 8; ++kk) {
    short8 af0 = *(const short8*)&Pb[fr * PBS + kk * 32 + fg * 8];
    short8 af1 = *(const short8*)&Pb[(16 + fr) * PBS + kk * 32 + fg * 8];
    short8 bfr;
    const float w = wyv[kk];
#pragma unroll
    for (int e = 0; e < 8; ++e) bfr[e] = f2bfs(w * xv[e]);
    acc0 = __builtin_amdgcn_mfma_f32_16x16x32_bf16(af0, bfr, acc0, 0, 0, 0);
    acc1 = __builtin_amdgcn_mfma_f32_16x16x32_bf16(af1, bfr, acc1, 0, 0, 0);
  }

  if (cell < 49) {
    unsigned short* xb = X + (size_t)box * 12544 + (size_t)(oct * 32) * 49 + cell;
#pragma unroll
    for (int q = 0; q < 4; ++q) {
      xb[(fg * 4 + q) * 49] = f2bf(acc0[q]);
      xb[(16 + fg * 4 + q) * 49] = f2bf(acc1[q]);
    }
  }
}

// ---------------- GEMM v3: 128x128 tile, BK=64, T2 XOR-swizzle, split-K, T1 XCD swizzle ----------------
template <int KSPLIT>
__global__ __launch_bounds__(256) void gemm_bt_swz(
    const unsigned short* __restrict__ A, const unsigned short* __restrict__ Bw,
    float* __restrict__ C, int M, int N, int K) {
  constexpr int BM = 128, BN = 128, BK = 64;
  __shared__ unsigned short As[BM * BK];   // 16 KB
  __shared__ unsigned short Bs[BN * BK];   // 16 KB

  const int tid = threadIdx.x;
  const int lane = tid & 63, wid = tid >> 6;
  const int wr = wid >> 1, wc = wid & 1;    // 2x2 waves, 64x64 each
  const int fr = lane & 15, fg = lane >> 4;

  // T1: XCD-aware block swizzle (bijective since nwg % 8 == 0)
  int bx = blockIdx.x, by = blockIdx.y, bz = blockIdx.z;
  {
    const int gx = gridDim.x, gy = gridDim.y;
    const int nwg = gx * gy * gridDim.z;
    if ((nwg & 7) == 0) {
      int lin = bx + gx * (by + gy * bz);
      int swz = (lin & 7) * (nwg >> 3) + (lin >> 3);
      bx = swz % gx;
      int t = swz / gx;
      by = t % gy;
      bz = t / gy;
    }
  }
  const int tm = bx * BM, tn = by * BN;

  const int kLen = K / KSPLIT;
  const int kTiles = kLen / BK;
  const int kBeg = bz * kLen;
  float* Cz = C + (size_t)bz * M * N;

  floatx4 acc[4][4];
#pragma unroll
  for (int i = 0; i < 4; ++i)
#pragma unroll
    for (int j = 0; j < 4; ++j)
      acc[i][j] = (floatx4){0.f, 0.f, 0.f, 0.f};

  for (int t = 0; t < kTiles; ++t) {
    const int k0 = kBeg + t * BK;
#pragma unroll
    for (int s = tid; s < BM * 8; s += 256) {
      int row = s >> 3, sl = s & 7;
      int slg = sl ^ (row & 7);
      gload16(&A[(size_t)(tm + row) * K + k0 + slg * 8], &As[s * 8]);
    }
#pragma unroll
    for (int s = tid; s < BN * 8; s += 256) {
      int row = s >> 3, sl = s & 7;
      int slg = sl ^ (row & 7);
      gload16(&Bw[(size_t)(tn + row) * K + k0 + slg * 8], &Bs[s * 8]);
    }
    __syncthreads();

#pragma unroll
    for (int kk = 0; kk < 2; ++kk) {
      short8 af[4], bf[4];
#pragma unroll
      for (int i = 0; i < 4; ++i) {
        int row = wr * 64 + i * 16 + fr;
        int sl = (kk * 4 + fg) ^ (row & 7);
        af[i] = *reinterpret_cast<const short8*>(&As[(row * 8 + sl) * 8]);
      }
#pragma unroll
      for (int j = 0; j < 4; ++j) {
        int row = wc * 64 + j * 16 + fr;
        int sl = (kk * 4 + fg) ^ (row & 7);
        bf[j] = *reinterpret_cast<const short8*>(&Bs[(row * 8 + sl) * 8]);
      }
#pragma unroll
      for (int i = 0; i < 4; ++i)
#pragma unroll
        for (int j = 0; j < 4; ++j)
          acc[i][j] = __builtin_amdgcn_mfma_f32_16x16x32_bf16(af[i], bf[j], acc[i][j], 0, 0, 0);
    }
    __syncthreads();
  }

#pragma unroll
  for (int i = 0; i < 4; ++i)
#pragma unroll
    for (int j = 0; j < 4; ++j)
#pragma unroll
      for (int q = 0; q < 4; ++q) {
        int rr = tm + wr * 64 + i * 16 + fg * 4 + q;
        int cc = tn + wc * 64 + j * 16 + fr;
        Cz[(size_t)rr * N + cc] = acc[i][j][q];
      }
}

// ---------------- old GEMM (pred head only) ----------------
template <int BM, int BN, int WAVES_M, int WAVES_N, int KSPLIT>
__global__ __launch_bounds__(256) void gemm_bt_kernel(
    const unsigned short* __restrict__ A, const unsigned short* __restrict__ Bw,
    float* __restrict__ C, int M, int N, int K) {
  constexpr int BK = 32;
  constexpr int WM = BM / WAVES_M, WN = BN / WAVES_N;
  constexpr int AF = WM / 16, BF = WN / 16;
  constexpr int ASLOT = BM * 4;
  constexpr int BSLOT = BN * 4;
  __shared__ unsigned short As[BM * BK];
  __shared__ unsigned short Bs[BN * BK];

  const int tid = threadIdx.x;
  const int lane = tid & 63, wid = tid >> 6;
  const int wr = wid / WAVES_N, wc = wid % WAVES_N;
  const int tm = blockIdx.x * BM, tn = blockIdx.y * BN;
  const int fr = lane & 15, fg = lane >> 4;

  const int kLen = K / KSPLIT;
  const int kBeg = blockIdx.z * kLen;
  float* Cz = C + (size_t)blockIdx.z * M * N;

  floatx4 acc[AF][BF];
#pragma unroll
  for (int i = 0; i < AF; ++i)
#pragma unroll
    for (int j = 0; j < BF; ++j)
      acc[i][j] = (floatx4){0.f, 0.f, 0.f, 0.f};

  for (int k0 = kBeg; k0 < kBeg + kLen; k0 += BK) {
#pragma unroll
    for (int s = tid; s < ASLOT; s += 256) {
      int row = s >> 2, kb = (s & 3) << 3;
      gload16(&A[(size_t)(tm + row) * K + k0 + kb], &As[s * 8]);
    }
#pragma unroll
    for (int s = tid; s < BSLOT; s += 256) {
      int row = s >> 2, kb = (s & 3) << 3;
      gload16(&Bw[(size_t)(tn + row) * K + k0 + kb], &Bs[s * 8]);
    }
    __syncthreads();

    short8 af[AF], bfv[BF];
#pragma unroll
    for (int i = 0; i < AF; ++i)
      af[i] = *reinterpret_cast<const short8*>(&As[(wr * WM + i * 16 + fr) * BK + fg * 8]);
#pragma unroll
    for (int j = 0; j < BF; ++j)
      bfv[j] = *reinterpret_cast<const short8*>(&Bs[(wc * WN + j * 16 + fr) * BK + fg * 8]);
#pragma unroll
    for (int i = 0; i < AF; ++i)
#pragma unroll
      for (int j = 0; j < BF; ++j)
        acc[i][j] = __builtin_amdgcn_mfma_f32_16x16x32_bf16(af[i], bfv[j], acc[i][j], 0, 0, 0);
    __syncthreads();
  }

#pragma unroll
  for (int i = 0; i < AF; ++i)
#pragma unroll
    for (int j = 0; j < BF; ++j)
#pragma unroll
      for (int q = 0; q < 4; ++q) {
        int rr = tm + wr * WM + i * 16 + fg * 4 + q;
        int cc = tn + wc * WN + j * 16 + fr;
        Cz[(size_t)rr * N + cc] = acc[i][j][q];
      }
}

// ---------------- BatchNorm (train mode) ----------------
// pass 1: reduce split-K partials + per-rowgroup stats. grid (Ncols/256, 128).
__global__ void bn_stats_red_kernel(const float* __restrict__ Yp, float* __restrict__ Yred,
                                    float* __restrict__ psum, float* __restrict__ psq,
                                    int Ncols, int rowsPer, int P, size_t pstride) {
  int c = blockIdx.x * blockDim.x + threadIdx.x;
  int r0 = blockIdx.y * rowsPer;
  float s = 0.f, ss = 0.f;
  for (int r = 0; r < rowsPer; ++r) {
    size_t idx = (size_t)(r0 + r) * Ncols + c;
    float v = Yp[idx];
    for (int p = 1; p < P; ++p) v += Yp[idx + (size_t)p * pstride];
    Yred[idx] = v;
    s += v;
    ss += v * v;
  }
  psum[(size_t)blockIdx.y * Ncols + c] = s;
  psq[(size_t)blockIdx.y * Ncols + c] = ss;
}

__global__ void bn_finalize_kernel(const float* __restrict__ psum, const float* __restrict__ psq,
                                   const float* __restrict__ g, const float* __restrict__ b,
                                   float* __restrict__ scale, float* __restrict__ shift,
                                   int Ncols, int P, float invM) {
  int c = blockIdx.x * blockDim.x + threadIdx.x;
  if (c >= Ncols) return;
  float s = 0.f, ss = 0.f;
  for (int p = 0; p < P; ++p) {
    s += psum[(size_t)p * Ncols + c];
    ss += psq[(size_t)p * Ncols + c];
  }
  float mean = s * invM;
  float var = ss * invM - mean * mean;
  float rstd = rsqrtf(var + 1e-5f);
  float sc = rstd * g[c];
  scale[c] = sc;
  shift[c] = b[c] - mean * sc;
}

// pass 2: apply, vectorized float4 -> 4x bf16 (FC divisible by 4)
__global__ void bn_apply4_kernel(const float4* __restrict__ Y, const float* __restrict__ scale,
                                 const float* __restrict__ shift, ushort4v* __restrict__ X,
                                 int colGroupsMask, int total4) {
  int i = blockIdx.x * blockDim.x + threadIdx.x;
  if (i >= total4) return;
  int c0 = (i & colGroupsMask) * 4;
  float4 v = Y[i];
  ushort4v o;
  o[0] = f2bf(fmaxf(v.x * scale[c0 + 0] + shift[c0 + 0], 0.0f));
  o[1] = f2bf(fmaxf(v.y * scale[c0 + 1] + shift[c0 + 1], 0.0f));
  o[2] = f2bf(fmaxf(v.z * scale[c0 + 2] + shift[c0 + 2], 0.0f));
  o[3] = f2bf(fmaxf(v.w * scale[c0 + 3] + shift[c0 + 3], 0.0f));
  X[i] = o;
}

// ---------------- decode ----------------
// Y3 holds KSPLIT=4 partials of (2048 x 96)
__global__ void decode_kernel(const float* __restrict__ Y3, const float* __restrict__ pb,
                              const float* __restrict__ anchors, const int* __restrict__ aid,
                              float* __restrict__ out) {
  int i = blockIdx.x * blockDim.x + threadIdx.x;
  if (i >= 2048 * 94) return;
  int bn = i / 94;
  int ch = i - bn * 94;
  size_t idx = (size_t)bn * 96 + ch;
  float v = Y3[idx] + Y3[idx + 2048 * 96] + Y3[idx + 2 * 2048 * 96] + Y3[idx + 3 * 2048 * 96];
  v += pb[ch];
  float o = v;
  if (ch >= 4 && ch < 22) {
    int q = ch - 4;
    int d = q % 6;   // within-class: 0,1=yx 2,3=lw 4,5=zh
    if (d < 2) {
      float stride_px = (float)(8 << (aid[bn] / 3));
      o = anchors[(size_t)bn * 4 + d] + v * stride_px;
    } else if (d < 4) {
      float cl = fminf(fmaxf(v, -4.0f), 4.0f);
      o = anchors[(size_t)bn * 4 + d] * expf(cl);
    }
  }
  out[i] = o;
}

// ---------------- launch ----------------
extern "C" void kernel_launch(void* const* d_in, const int* in_sizes, int n_in,
                              void* d_out, int out_size, void* d_ws, size_t ws_size,
                              hipStream_t stream) {
  const float* feat_p3   = (const float*)d_in[0];
  const float* feat_p4   = (const float*)d_in[1];
  const float* feat_p5   = (const float*)d_in[2];
  const float* bbox2d    = (const float*)d_in[3];
  const float* anchors   = (const float*)d_in[4];
  const int*   anchor_id = (const int*)d_in[5];
  const float* fc1_w     = (const float*)d_in[6];
  // d_in[7] fc1_b: cancels through train-mode BN (mean subtraction) — unused
  const float* bn1_g     = (const float*)d_in[8];
  const float* bn1_b     = (const float*)d_in[9];
  const float* fc2_w     = (const float*)d_in[10];
  // d_in[11] fc2_b: cancels — unused
  const float* bn2_g     = (const float*)d_in[12];
  const float* bn2_b     = (const float*)d_in[13];
  const float* pred_w    = (const float*)d_in[14];
  const float* pred_b    = (const float*)d_in[15];
  float* out = (float*)d_out;

  const int M = 2048;          // B*N
  const int K1 = 12544;        // 256*7*7
  const int FC = 1024;
  const int RG = 128;          // BN stats row-groups

  char* ws = (char*)d_ws;
  auto alloc = [&](size_t bytes) -> char* {
    char* p = ws;
    ws += (bytes + 255) & ~(size_t)255;
    return p;
  };
  unsigned short* W1b  = (unsigned short*)alloc((size_t)FC * K1 * 2);
  unsigned short* W2b  = (unsigned short*)alloc((size_t)FC * FC * 2);
  unsigned short* W3b  = (unsigned short*)alloc((size_t)96 * FC * 2);
  unsigned short* X1   = (unsigned short*)alloc((size_t)M * K1 * 2);
  float*          Yp   = (float*)alloc((size_t)4 * M * FC * 4);  // split-K partials
  float*          Yr   = (float*)alloc((size_t)M * FC * 4);      // reduced Y
  unsigned short* X2   = (unsigned short*)alloc((size_t)M * FC * 2);
  unsigned short* X3   = (unsigned short*)alloc((size_t)M * FC * 2);
  float*          Y3   = (float*)alloc((size_t)4 * M * 96 * 4);
  float*          ps   = (float*)alloc((size_t)RG * FC * 4);
  float*          pq   = (float*)alloc((size_t)RG * FC * 4);
  float*          sc1  = (float*)alloc((size_t)FC * 4);
  float*          sh1  = (float*)alloc((size_t)FC * 4);
  float*          sc2  = (float*)alloc((size_t)FC * 4);
  float*          sh2  = (float*)alloc((size_t)FC * 4);

  // fused: weight conversions (overlapped) + ROI align -> X1
  prep_roi_kernel<<<GRID_TOTAL, 256, 0, stream>>>(
      feat_p3, feat_p4, feat_p5, bbox2d, anchor_id, X1,
      fc1_w, W1b, fc2_w, W2b, pred_w, W3b);

  // fc1: X1 (2048x12544) @ W1^T -> Yp (4 partials of 2048x1024)
  gemm_bt_swz<4><<<dim3(M / 128, FC / 128, 4), 256, 0, stream>>>(X1, W1b, Yp, M, FC, K1);

  // BN1: reduce partials + stats (512 blocks), finalize, apply+ReLU -> X2 bf16
  bn_stats_red_kernel<<<dim3(FC / 256, RG), 256, 0, stream>>>(Yp, Yr, ps, pq, FC, M / RG, 4, (size_t)M * FC);
  bn_finalize_kernel<<<FC / 256, 256, 0, stream>>>(ps, pq, bn1_g, bn1_b, sc1, sh1, FC, RG, 1.0f / M);
  bn_apply4_kernel<<<(M * FC / 4) / 256, 256, 0, stream>>>(
      (const float4*)Yr, sc1, sh1, (ushort4v*)X2, FC / 4 - 1, M * FC / 4);

  // fc2: X2 @ W2^T -> Yp (2 partials)
  gemm_bt_swz<2><<<dim3(M / 128, FC / 128, 2), 256, 0, stream>>>(X2, W2b, Yp, M, FC, FC);

  // BN2 + ReLU -> X3 bf16
  bn_stats_red_kernel<<<dim3(FC / 256, RG), 256, 0, stream>>>(Yp, Yr, ps, pq, FC, M / RG, 2, (size_t)M * FC);
  bn_finalize_kernel<<<FC / 256, 256, 0, stream>>>(ps, pq, bn2_g, bn2_b, sc2, sh2, FC, RG, 1.0f / M);
  bn_apply4_kernel<<<(M * FC / 4) / 256, 256, 0, stream>>>(
      (const float4*)Yr, sc2, sh2, (ushort4v*)X3, FC / 4 - 1, M * FC / 4);

  // pred head: X3 @ W3p^T -> Y3 (split-K=4 partials of 2048 x 96)
  gemm_bt_kernel<64, 96, 2, 2, 4><<<dim3(M / 64, 1, 4), 256, 0, stream>>>(X3, W3b, Y3, M, 96, FC);

  // decode -> out (2048 x 94)
  decode_kernel<<<(2048 * 94 + 255) / 256, 256, 0, stream>>>(Y3, pred_b, anchors, anchor_id, out);
}

// Round 14
// 243.886 us; speedup vs baseline: 1.3285x; 1.0295x over previous
//
#include <hip/hip_runtime.h>
#include <hip/hip_bf16.h>

typedef __attribute__((ext_vector_type(8))) short short8;
typedef __attribute__((ext_vector_type(4))) float floatx4;
typedef __attribute__((ext_vector_type(4))) unsigned short ushort4v;

#define DEVI __device__ __forceinline__

// ---------------- constants ----------------
// B=4, N=512, C_IN=256, RES=7, SR=2, FC_DIM=1024, OUT_CH=94
// M = B*N = 2048 rows, K1 = 256*7*7 = 12544

DEVI unsigned short f2bf(float v) {
  union { __hip_bfloat16 h; unsigned short u; } cv;
  cv.h = __float2bfloat16(v);
  return cv.u;
}
DEVI short f2bfs(float v) { return (short)f2bf(v); }

DEVI void gload16(const void* gptr, void* lptr) {
  __builtin_amdgcn_global_load_lds(
      (const __attribute__((address_space(1))) unsigned int*)gptr,
      (__attribute__((address_space(3))) unsigned int*)(unsigned long long)(uintptr_t)lptr,
      16, 0, 0);
}

// ---------------- fused prep + ROI align ----------------
// Block ranges (uniform branch per block):
//   [0, 16384)          : ROI align, box = bid&2047, oct = bid>>11
//   [16384, 28928)      : cvt fc1_w f32->bf16
//   [28928, 29952)      : cvt fc2_w f32->bf16
//   [29952, 30336)      : pred_w pad-cvt
// ROI has two per-block-uniform paths: 16x16 patch (K=256) and, when the
// sample span fits, an 8x8 patch (K=64) — 1/4 the staging and MFMA work.
#define ROI_BLKS   16384
#define CVT1_END   28928
#define CVT2_END   29952
#define GRID_TOTAL 30336

__global__ __launch_bounds__(256) void prep_roi_kernel(
    const float* __restrict__ p3, const float* __restrict__ p4,
    const float* __restrict__ p5, const float* __restrict__ bbox,
    const int* __restrict__ aid, unsigned short* __restrict__ X,
    const float* __restrict__ fc1_w, unsigned short* __restrict__ W1b,
    const float* __restrict__ fc2_w, unsigned short* __restrict__ W2b,
    const float* __restrict__ pred_w, unsigned short* __restrict__ W3b) {
  constexpr int PS = 260;   // slow: f32 per-channel stride
  constexpr int PBS = 280;  // slow: bf16 per-channel stride (560 B)
  constexpr int PS8 = 260;  // fast: f32 per-GROUP(4ch) stride (4*64+4 pad)
  constexpr int PBS8 = 72;  // fast: bf16 per-channel stride (144 B)
  __shared__ float Pf[32 * PS];            // 33280 B; Pb overlays it
  __shared__ float wyx[238];               // wy [7][17] @0, wx [7][17] @119
  __shared__ int sy0[14], sx0[14];
  __shared__ float sly[14], slx[14];

  const int bid = blockIdx.x;
  const int tid = threadIdx.x;

  if (bid >= ROI_BLKS) {
    if (bid < CVT1_END) {
      size_t i = (size_t)(bid - ROI_BLKS) * 256 + tid;
      float4 v = ((const float4*)fc1_w)[i];
      ushort4v o;
      o[0] = f2bf(v.x); o[1] = f2bf(v.y); o[2] = f2bf(v.z); o[3] = f2bf(v.w);
      ((ushort4v*)W1b)[i] = o;
    } else if (bid < CVT2_END) {
      size_t i = (size_t)(bid - CVT1_END) * 256 + tid;
      float4 v = ((const float4*)fc2_w)[i];
      ushort4v o;
      o[0] = f2bf(v.x); o[1] = f2bf(v.y); o[2] = f2bf(v.z); o[3] = f2bf(v.w);
      ((ushort4v*)W2b)[i] = o;
    } else {
      int i = (bid - CVT2_END) * 256 + tid;
      int row = i >> 10;
      W3b[i] = (row < 94) ? f2bf(pred_w[i]) : (unsigned short)0;
    }
    return;
  }

  // ---------------- ROI branch ----------------
  unsigned short* Pb = (unsigned short*)Pf;
  const int box = bid & 2047;
  const int oct = bid >> 11;               // channels oct*32 ..
  const int b = box >> 9;
  const int lane = tid & 63, wid = tid >> 6;

  const int lvl = aid[box] / 3;
  const int H = 64 >> lvl;
  const int HH = H * H;
  const float* base = (lvl == 0) ? p3 : ((lvl == 1) ? p4 : p5);
  const float scale = 0.125f / (float)(1 << lvl);

  // ---- phase A: sample grid ----
  if (tid < 28) {
    int s = tid;
    bool isY = s < 14;
    int k = isY ? s : s - 14;
    float lo = bbox[box * 4 + (isY ? 0 : 1)];
    float hi = bbox[box * 4 + (isY ? 2 : 3)];
    float t = lo * scale - 0.5f;
    float cell = (hi - lo) * scale * (1.0f / 7.0f);
    float pos = t + ((float)k + 0.5f) * 0.5f * cell;   // S=14 samples, SR=2
    pos = fminf(fmaxf(pos, 0.0f), (float)(H - 1));
    int i0 = (int)floorf(pos);
    if (i0 > H - 2) i0 = H - 2;        // fr=1 reproduces the clamp
    float fr = pos - (float)i0;
    if (isY) { sy0[k] = i0; sly[k] = fr; }
    else     { sx0[k] = i0; slx[k] = fr; }
  }
  __syncthreads();

  // fast path iff the whole sample footprint (incl. +1 taps) fits an 8x8 patch
  const int ry8 = min(sy0[0], H - 8), rx8 = min(sx0[0], H - 8);
  const bool fast = (sy0[13] - ry8 <= 6) && (sx0[13] - rx8 <= 6);
  const int ryb = fast ? ry8 : min(sy0[0], H - 16);
  const int rxb = fast ? rx8 : min(sx0[0], H - 16);
  const float* fb = base + ((size_t)b * 256 + oct * 32) * HH + ryb * H + rxb;

  // ---- phase B1: separable pooled weights wy[7][16], wx[7][16] (stride 17) ----
  if (tid < 224) {
    int j = tid;
    bool isY = j < 112;
    int k2 = isY ? j : j - 112;
    int py = k2 >> 4, r = k2 & 15;
    int o0 = isY ? ryb : rxb;
    float acc = 0.f;
#pragma unroll
    for (int ss = 0; ss < 2; ++ss) {
      int s = 2 * py + ss;
      int rel = (isY ? sy0[s] : sx0[s]) - o0;
      float fr = isY ? sly[s] : slx[s];
      if (r == rel)     acc += 1.0f - fr;
      if (r == rel + 1) acc += fr;
    }
    wyx[(isY ? 0 : 119) + py * 17 + r] = acc * 0.5f;
  }

  const int fr = lane & 15, fg = lane >> 4;
  const int cell = wid * 16 + fr;          // 0..63; valid < 49
  const int py = (cell * 37) >> 8;         // cell/7 for 0..63 (py<=9: garbage, masked)
  const int px = cell - py * 7;

  floatx4 acc0 = (floatx4){0.f, 0.f, 0.f, 0.f};   // channels 0..15
  floatx4 acc1 = (floatx4){0.f, 0.f, 0.f, 0.f};   // channels 16..31

  if (fast) {
    // ---- FAST: 8x8 patch, K=64 ----
    // stage: 4 channels per wave-op (256B each); group(4ch) stride PS8 f32
    {
      const int r8 = (lane & 15) >> 1, c8 = (lane & 1) * 4, lch = lane >> 4;
      const float* s8 = fb + r8 * H + c8;
#pragma unroll
      for (int it = 0; it < 2; ++it) {
        int grp = it * 4 + wid;
        gload16(s8 + (size_t)(grp * 4 + lch) * HH, &Pf[grp * PS8] + lane * 4);
      }
    }
    __syncthreads();

    // cvt-once in place: thread -> ch = tid&31, half hf = tid>>5 (8 f32)
    {
      const int cch = tid & 31, hf = tid >> 5;
      const float* src = &Pf[(cch >> 2) * PS8 + (cch & 3) * 64 + hf * 8];
      floatx4 v0 = *(const floatx4*)src, v1 = *(const floatx4*)(src + 4);
      __syncthreads();
      unsigned int d0 = (unsigned int)f2bf(v0[0]) | ((unsigned int)f2bf(v0[1]) << 16);
      unsigned int d1 = (unsigned int)f2bf(v0[2]) | ((unsigned int)f2bf(v0[3]) << 16);
      unsigned int d2 = (unsigned int)f2bf(v1[0]) | ((unsigned int)f2bf(v1[1]) << 16);
      unsigned int d3 = (unsigned int)f2bf(v1[2]) | ((unsigned int)f2bf(v1[3]) << 16);
      *(uint4*)&Pb[cch * PBS8 + hf * 8] = make_uint4(d0, d1, d2, d3);
    }

    // hoist B invariants: full wx row + 2 wy values (r = kk*4+fg)
    float xv[8];
    const float* xp = &wyx[119 + px * 17];
#pragma unroll
    for (int e = 0; e < 8; ++e) xv[e] = xp[e];
    const float w0 = wyx[py * 17 + fg];
    const float w1 = wyx[py * 17 + 4 + fg];
    __syncthreads();

#pragma unroll
    for (int kk = 0; kk < 2; ++kk) {
      short8 af0 = *(const short8*)&Pb[fr * PBS8 + kk * 32 + fg * 8];
      short8 af1 = *(const short8*)&Pb[(16 + fr) * PBS8 + kk * 32 + fg * 8];
      short8 bfr;
      const float w = kk ? w1 : w0;
#pragma unroll
      for (int e = 0; e < 8; ++e) bfr[e] = f2bfs(w * xv[e]);
      acc0 = __builtin_amdgcn_mfma_f32_16x16x32_bf16(af0, bfr, acc0, 0, 0, 0);
      acc1 = __builtin_amdgcn_mfma_f32_16x16x32_bf16(af1, bfr, acc1, 0, 0, 0);
    }
  } else {
    // ---- SLOW: 16x16 patch, K=256 (proven roi_mm6 path) ----
    {
      const int r = lane >> 2, c4 = (lane & 3) * 4;
      const float* src0 = fb + r * H + c4;
#pragma unroll
      for (int it = 0; it < 8; ++it) {
        int ch = it * 4 + wid;
        gload16(src0 + (size_t)ch * HH, &Pf[ch * PS] + lane * 4);
      }
    }
    __syncthreads();

    {
      const int cch = tid & 31, rp = tid >> 5;
      const float* src = &Pf[cch * PS + rp * 32];
      floatx4 v[8];
#pragma unroll
      for (int m = 0; m < 8; ++m) v[m] = *(const floatx4*)(src + 4 * m);
      __syncthreads();
      unsigned int d[16];
#pragma unroll
      for (int m = 0; m < 8; ++m) {
        d[2 * m]     = (unsigned int)f2bf(v[m][0]) | ((unsigned int)f2bf(v[m][1]) << 16);
        d[2 * m + 1] = (unsigned int)f2bf(v[m][2]) | ((unsigned int)f2bf(v[m][3]) << 16);
      }
      unsigned short* dst = &Pb[cch * PBS + rp * 32];
#pragma unroll
      for (int m = 0; m < 4; ++m)
        *(uint4*)(dst + m * 8) = make_uint4(d[4 * m], d[4 * m + 1], d[4 * m + 2], d[4 * m + 3]);
    }

    float xv[8], wyv[8];
    {
      const float* xp = &wyx[119 + px * 17 + (fg & 1) * 8];
#pragma unroll
      for (int e = 0; e < 8; ++e) xv[e] = xp[e];
      const float* wp = &wyx[py * 17 + (fg >> 1)];
#pragma unroll
      for (int kk = 0; kk < 8; ++kk) wyv[kk] = wp[2 * kk];
    }
    __syncthreads();

#pragma unroll
    for (int kk = 0; kk < 8; ++kk) {
      short8 af0 = *(const short8*)&Pb[fr * PBS + kk * 32 + fg * 8];
      short8 af1 = *(const short8*)&Pb[(16 + fr) * PBS + kk * 32 + fg * 8];
      short8 bfr;
      const float w = wyv[kk];
#pragma unroll
      for (int e = 0; e < 8; ++e) bfr[e] = f2bfs(w * xv[e]);
      acc0 = __builtin_amdgcn_mfma_f32_16x16x32_bf16(af0, bfr, acc0, 0, 0, 0);
      acc1 = __builtin_amdgcn_mfma_f32_16x16x32_bf16(af1, bfr, acc1, 0, 0, 0);
    }
  }

  if (cell < 49) {
    unsigned short* xb = X + (size_t)box * 12544 + (size_t)(oct * 32) * 49 + cell;
#pragma unroll
    for (int q = 0; q < 4; ++q) {
      xb[(fg * 4 + q) * 49] = f2bf(acc0[q]);
      xb[(16 + fg * 4 + q) * 49] = f2bf(acc1[q]);
    }
  }
}

// ---------------- GEMM v3: 128x128 tile, BK=64, T2 XOR-swizzle, split-K, T1 XCD swizzle ----------------
template <int KSPLIT>
__global__ __launch_bounds__(256) void gemm_bt_swz(
    const unsigned short* __restrict__ A, const unsigned short* __restrict__ Bw,
    float* __restrict__ C, int M, int N, int K) {
  constexpr int BM = 128, BN = 128, BK = 64;
  __shared__ unsigned short As[BM * BK];   // 16 KB
  __shared__ unsigned short Bs[BN * BK];   // 16 KB

  const int tid = threadIdx.x;
  const int lane = tid & 63, wid = tid >> 6;
  const int wr = wid >> 1, wc = wid & 1;    // 2x2 waves, 64x64 each
  const int fr = lane & 15, fg = lane >> 4;

  // T1: XCD-aware block swizzle (bijective since nwg % 8 == 0)
  int bx = blockIdx.x, by = blockIdx.y, bz = blockIdx.z;
  {
    const int gx = gridDim.x, gy = gridDim.y;
    const int nwg = gx * gy * gridDim.z;
    if ((nwg & 7) == 0) {
      int lin = bx + gx * (by + gy * bz);
      int swz = (lin & 7) * (nwg >> 3) + (lin >> 3);
      bx = swz % gx;
      int t = swz / gx;
      by = t % gy;
      bz = t / gy;
    }
  }
  const int tm = bx * BM, tn = by * BN;

  const int kLen = K / KSPLIT;
  const int kTiles = kLen / BK;
  const int kBeg = bz * kLen;
  float* Cz = C + (size_t)bz * M * N;

  floatx4 acc[4][4];
#pragma unroll
  for (int i = 0; i < 4; ++i)
#pragma unroll
    for (int j = 0; j < 4; ++j)
      acc[i][j] = (floatx4){0.f, 0.f, 0.f, 0.f};

  for (int t = 0; t < kTiles; ++t) {
    const int k0 = kBeg + t * BK;
#pragma unroll
    for (int s = tid; s < BM * 8; s += 256) {
      int row = s >> 3, sl = s & 7;
      int slg = sl ^ (row & 7);
      gload16(&A[(size_t)(tm + row) * K + k0 + slg * 8], &As[s * 8]);
    }
#pragma unroll
    for (int s = tid; s < BN * 8; s += 256) {
      int row = s >> 3, sl = s & 7;
      int slg = sl ^ (row & 7);
      gload16(&Bw[(size_t)(tn + row) * K + k0 + slg * 8], &Bs[s * 8]);
    }
    __syncthreads();

#pragma unroll
    for (int kk = 0; kk < 2; ++kk) {
      short8 af[4], bf[4];
#pragma unroll
      for (int i = 0; i < 4; ++i) {
        int row = wr * 64 + i * 16 + fr;
        int sl = (kk * 4 + fg) ^ (row & 7);
        af[i] = *reinterpret_cast<const short8*>(&As[(row * 8 + sl) * 8]);
      }
#pragma unroll
      for (int j = 0; j < 4; ++j) {
        int row = wc * 64 + j * 16 + fr;
        int sl = (kk * 4 + fg) ^ (row & 7);
        bf[j] = *reinterpret_cast<const short8*>(&Bs[(row * 8 + sl) * 8]);
      }
#pragma unroll
      for (int i = 0; i < 4; ++i)
#pragma unroll
        for (int j = 0; j < 4; ++j)
          acc[i][j] = __builtin_amdgcn_mfma_f32_16x16x32_bf16(af[i], bf[j], acc[i][j], 0, 0, 0);
    }
    __syncthreads();
  }

#pragma unroll
  for (int i = 0; i < 4; ++i)
#pragma unroll
    for (int j = 0; j < 4; ++j)
#pragma unroll
      for (int q = 0; q < 4; ++q) {
        int rr = tm + wr * 64 + i * 16 + fg * 4 + q;
        int cc = tn + wc * 64 + j * 16 + fr;
        Cz[(size_t)rr * N + cc] = acc[i][j][q];
      }
}

// ---------------- old GEMM (pred head only) ----------------
template <int BM, int BN, int WAVES_M, int WAVES_N, int KSPLIT>
__global__ __launch_bounds__(256) void gemm_bt_kernel(
    const unsigned short* __restrict__ A, const unsigned short* __restrict__ Bw,
    float* __restrict__ C, int M, int N, int K) {
  constexpr int BK = 32;
  constexpr int WM = BM / WAVES_M, WN = BN / WAVES_N;
  constexpr int AF = WM / 16, BF = WN / 16;
  constexpr int ASLOT = BM * 4;
  constexpr int BSLOT = BN * 4;
  __shared__ unsigned short As[BM * BK];
  __shared__ unsigned short Bs[BN * BK];

  const int tid = threadIdx.x;
  const int lane = tid & 63, wid = tid >> 6;
  const int wr = wid / WAVES_N, wc = wid % WAVES_N;
  const int tm = blockIdx.x * BM, tn = blockIdx.y * BN;
  const int fr = lane & 15, fg = lane >> 4;

  const int kLen = K / KSPLIT;
  const int kBeg = blockIdx.z * kLen;
  float* Cz = C + (size_t)blockIdx.z * M * N;

  floatx4 acc[AF][BF];
#pragma unroll
  for (int i = 0; i < AF; ++i)
#pragma unroll
    for (int j = 0; j < BF; ++j)
      acc[i][j] = (floatx4){0.f, 0.f, 0.f, 0.f};

  for (int k0 = kBeg; k0 < kBeg + kLen; k0 += BK) {
#pragma unroll
    for (int s = tid; s < ASLOT; s += 256) {
      int row = s >> 2, kb = (s & 3) << 3;
      gload16(&A[(size_t)(tm + row) * K + k0 + kb], &As[s * 8]);
    }
#pragma unroll
    for (int s = tid; s < BSLOT; s += 256) {
      int row = s >> 2, kb = (s & 3) << 3;
      gload16(&Bw[(size_t)(tn + row) * K + k0 + kb], &Bs[s * 8]);
    }
    __syncthreads();

    short8 af[AF], bfv[BF];
#pragma unroll
    for (int i = 0; i < AF; ++i)
      af[i] = *reinterpret_cast<const short8*>(&As[(wr * WM + i * 16 + fr) * BK + fg * 8]);
#pragma unroll
    for (int j = 0; j < BF; ++j)
      bfv[j] = *reinterpret_cast<const short8*>(&Bs[(wc * WN + j * 16 + fr) * BK + fg * 8]);
#pragma unroll
    for (int i = 0; i < AF; ++i)
#pragma unroll
      for (int j = 0; j < BF; ++j)
        acc[i][j] = __builtin_amdgcn_mfma_f32_16x16x32_bf16(af[i], bfv[j], acc[i][j], 0, 0, 0);
    __syncthreads();
  }

#pragma unroll
  for (int i = 0; i < AF; ++i)
#pragma unroll
    for (int j = 0; j < BF; ++j)
#pragma unroll
      for (int q = 0; q < 4; ++q) {
        int rr = tm + wr * WM + i * 16 + fg * 4 + q;
        int cc = tn + wc * WN + j * 16 + fr;
        Cz[(size_t)rr * N + cc] = acc[i][j][q];
      }
}

// ---------------- BatchNorm (train mode) ----------------
__global__ void bn_stats_red_kernel(const float* __restrict__ Yp, float* __restrict__ Yred,
                                    float* __restrict__ psum, float* __restrict__ psq,
                                    int Ncols, int rowsPer, int P, size_t pstride) {
  int c = blockIdx.x * blockDim.x + threadIdx.x;
  int r0 = blockIdx.y * rowsPer;
  float s = 0.f, ss = 0.f;
  for (int r = 0; r < rowsPer; ++r) {
    size_t idx = (size_t)(r0 + r) * Ncols + c;
    float v = Yp[idx];
    for (int p = 1; p < P; ++p) v += Yp[idx + (size_t)p * pstride];
    Yred[idx] = v;
    s += v;
    ss += v * v;
  }
  psum[(size_t)blockIdx.y * Ncols + c] = s;
  psq[(size_t)blockIdx.y * Ncols + c] = ss;
}

__global__ void bn_finalize_kernel(const float* __restrict__ psum, const float* __restrict__ psq,
                                   const float* __restrict__ g, const float* __restrict__ b,
                                   float* __restrict__ scale, float* __restrict__ shift,
                                   int Ncols, int P, float invM) {
  int c = blockIdx.x * blockDim.x + threadIdx.x;
  if (c >= Ncols) return;
  float s = 0.f, ss = 0.f;
  for (int p = 0; p < P; ++p) {
    s += psum[(size_t)p * Ncols + c];
    ss += psq[(size_t)p * Ncols + c];
  }
  float mean = s * invM;
  float var = ss * invM - mean * mean;
  float rstd = rsqrtf(var + 1e-5f);
  float sc = rstd * g[c];
  scale[c] = sc;
  shift[c] = b[c] - mean * sc;
}

__global__ void bn_apply4_kernel(const float4* __restrict__ Y, const float* __restrict__ scale,
                                 const float* __restrict__ shift, ushort4v* __restrict__ X,
                                 int colGroupsMask, int total4) {
  int i = blockIdx.x * blockDim.x + threadIdx.x;
  if (i >= total4) return;
  int c0 = (i & colGroupsMask) * 4;
  float4 v = Y[i];
  ushort4v o;
  o[0] = f2bf(fmaxf(v.x * scale[c0 + 0] + shift[c0 + 0], 0.0f));
  o[1] = f2bf(fmaxf(v.y * scale[c0 + 1] + shift[c0 + 1], 0.0f));
  o[2] = f2bf(fmaxf(v.z * scale[c0 + 2] + shift[c0 + 2], 0.0f));
  o[3] = f2bf(fmaxf(v.w * scale[c0 + 3] + shift[c0 + 3], 0.0f));
  X[i] = o;
}

// ---------------- decode ----------------
__global__ void decode_kernel(const float* __restrict__ Y3, const float* __restrict__ pb,
                              const float* __restrict__ anchors, const int* __restrict__ aid,
                              float* __restrict__ out) {
  int i = blockIdx.x * blockDim.x + threadIdx.x;
  if (i >= 2048 * 94) return;
  int bn = i / 94;
  int ch = i - bn * 94;
  size_t idx = (size_t)bn * 96 + ch;
  float v = Y3[idx] + Y3[idx + 2048 * 96] + Y3[idx + 2 * 2048 * 96] + Y3[idx + 3 * 2048 * 96];
  v += pb[ch];
  float o = v;
  if (ch >= 4 && ch < 22) {
    int q = ch - 4;
    int d = q % 6;   // within-class: 0,1=yx 2,3=lw 4,5=zh
    if (d < 2) {
      float stride_px = (float)(8 << (aid[bn] / 3));
      o = anchors[(size_t)bn * 4 + d] + v * stride_px;
    } else if (d < 4) {
      float cl = fminf(fmaxf(v, -4.0f), 4.0f);
      o = anchors[(size_t)bn * 4 + d] * expf(cl);
    }
  }
  out[i] = o;
}

// ---------------- launch ----------------
extern "C" void kernel_launch(void* const* d_in, const int* in_sizes, int n_in,
                              void* d_out, int out_size, void* d_ws, size_t ws_size,
                              hipStream_t stream) {
  const float* feat_p3   = (const float*)d_in[0];
  const float* feat_p4   = (const float*)d_in[1];
  const float* feat_p5   = (const float*)d_in[2];
  const float* bbox2d    = (const float*)d_in[3];
  const float* anchors   = (const float*)d_in[4];
  const int*   anchor_id = (const int*)d_in[5];
  const float* fc1_w     = (const float*)d_in[6];
  // d_in[7] fc1_b: cancels through train-mode BN (mean subtraction) — unused
  const float* bn1_g     = (const float*)d_in[8];
  const float* bn1_b     = (const float*)d_in[9];
  const float* fc2_w     = (const float*)d_in[10];
  // d_in[11] fc2_b: cancels — unused
  const float* bn2_g     = (const float*)d_in[12];
  const float* bn2_b     = (const float*)d_in[13];
  const float* pred_w    = (const float*)d_in[14];
  const float* pred_b    = (const float*)d_in[15];
  float* out = (float*)d_out;

  const int M = 2048;          // B*N
  const int K1 = 12544;        // 256*7*7
  const int FC = 1024;
  const int RG = 128;          // BN stats row-groups

  char* ws = (char*)d_ws;
  auto alloc = [&](size_t bytes) -> char* {
    char* p = ws;
    ws += (bytes + 255) & ~(size_t)255;
    return p;
  };
  unsigned short* W1b  = (unsigned short*)alloc((size_t)FC * K1 * 2);
  unsigned short* W2b  = (unsigned short*)alloc((size_t)FC * FC * 2);
  unsigned short* W3b  = (unsigned short*)alloc((size_t)96 * FC * 2);
  unsigned short* X1   = (unsigned short*)alloc((size_t)M * K1 * 2);
  float*          Yp   = (float*)alloc((size_t)4 * M * FC * 4);  // split-K partials
  float*          Yr   = (float*)alloc((size_t)M * FC * 4);      // reduced Y
  unsigned short* X2   = (unsigned short*)alloc((size_t)M * FC * 2);
  unsigned short* X3   = (unsigned short*)alloc((size_t)M * FC * 2);
  float*          Y3   = (float*)alloc((size_t)4 * M * 96 * 4);
  float*          ps   = (float*)alloc((size_t)RG * FC * 4);
  float*          pq   = (float*)alloc((size_t)RG * FC * 4);
  float*          sc1  = (float*)alloc((size_t)FC * 4);
  float*          sh1  = (float*)alloc((size_t)FC * 4);
  float*          sc2  = (float*)alloc((size_t)FC * 4);
  float*          sh2  = (float*)alloc((size_t)FC * 4);

  // fused: weight conversions (overlapped) + ROI align -> X1
  prep_roi_kernel<<<GRID_TOTAL, 256, 0, stream>>>(
      feat_p3, feat_p4, feat_p5, bbox2d, anchor_id, X1,
      fc1_w, W1b, fc2_w, W2b, pred_w, W3b);

  // fc1: X1 (2048x12544) @ W1^T -> Yp (4 partials of 2048x1024)
  gemm_bt_swz<4><<<dim3(M / 128, FC / 128, 4), 256, 0, stream>>>(X1, W1b, Yp, M, FC, K1);

  // BN1: reduce partials + stats (512 blocks), finalize, apply+ReLU -> X2 bf16
  bn_stats_red_kernel<<<dim3(FC / 256, RG), 256, 0, stream>>>(Yp, Yr, ps, pq, FC, M / RG, 4, (size_t)M * FC);
  bn_finalize_kernel<<<FC / 256, 256, 0, stream>>>(ps, pq, bn1_g, bn1_b, sc1, sh1, FC, RG, 1.0f / M);
  bn_apply4_kernel<<<(M * FC / 4) / 256, 256, 0, stream>>>(
      (const float4*)Yr, sc1, sh1, (ushort4v*)X2, FC / 4 - 1, M * FC / 4);

  // fc2: X2 @ W2^T -> Yp (2 partials)
  gemm_bt_swz<2><<<dim3(M / 128, FC / 128, 2), 256, 0, stream>>>(X2, W2b, Yp, M, FC, FC);

  // BN2 + ReLU -> X3 bf16
  bn_stats_red_kernel<<<dim3(FC / 256, RG), 256, 0, stream>>>(Yp, Yr, ps, pq, FC, M / RG, 2, (size_t)M * FC);
  bn_finalize_kernel<<<FC / 256, 256, 0, stream>>>(ps, pq, bn2_g, bn2_b, sc2, sh2, FC, RG, 1.0f / M);
  bn_apply4_kernel<<<(M * FC / 4) / 256, 256, 0, stream>>>(
      (const float4*)Yr, sc2, sh2, (ushort4v*)X3, FC / 4 - 1, M * FC / 4);

  // pred head: X3 @ W3p^T -> Y3 (split-K=4 partials of 2048 x 96)
  gemm_bt_kernel<64, 96, 2, 2, 4><<<dim3(M / 64, 1, 4), 256, 0, stream>>>(X3, W3b, Y3, M, 96, FC);

  // decode -> out (2048 x 94)
  decode_kernel<<<(2048 * 94 + 255) / 256, 256, 0, stream>>>(Y3, pred_b, anchors, anchor_id, out);
}